// Round 1
// baseline (544.872 us; speedup 1.0000x reference)
//
#include <hip/hip_runtime.h>
#include <hip/hip_bf16.h>

#define N_NODES 50000
#define N_EDGES 800000
#define E_TOT   850000   /* N_EDGES + N_NODES self-loops */
#define C_IN    512
#define C_HID   128
#define HEADS2  3
#define NEG     0.2f

__device__ __forceinline__ float leaky(float x) { return x > 0.f ? x : NEG * x; }

// ---------------------------------------------------------------------------
// lin1: h1 = x @ W1   (M=50000, K=512, N=128) fp32 SGEMM
// 64x128 block tile, 256 threads, 8x4 per-thread tile, BK=32
// ---------------------------------------------------------------------------
#define BM 64
#define BN 128
#define BK 32
__global__ __launch_bounds__(256) void lin1_kernel(const float* __restrict__ x,
                                                   const float* __restrict__ W,
                                                   float* __restrict__ h1) {
  __shared__ float xs[BK][BM + 4];   // transposed x tile, stride 68 (16B-aligned rows)
  __shared__ float ws[BK][BN];
  const int tid = threadIdx.x;
  const int m0  = blockIdx.x * BM;
  const int cg  = tid & 31;          // 32 col groups * 4 cols
  const int rg  = tid >> 5;          // 8 row groups * 8 rows

  float acc[8][4];
#pragma unroll
  for (int r = 0; r < 8; r++)
#pragma unroll
    for (int c = 0; c < 4; c++) acc[r][c] = 0.f;

  // staging map: row lr = tid>>2 (64 rows), k-segment lk = (tid&3)*8
  const int lr = tid >> 2;
  const int lk = (tid & 3) * 8;
  int grow = m0 + lr;
  if (grow >= N_NODES) grow = N_NODES - 1;   // clamp; stores are guarded
  const float* xrow = x + (size_t)grow * C_IN;

  for (int k0 = 0; k0 < C_IN; k0 += BK) {
    float4 xa = *(const float4*)(xrow + k0 + lk);
    float4 xb = *(const float4*)(xrow + k0 + lk + 4);
    xs[lk + 0][lr] = xa.x; xs[lk + 1][lr] = xa.y; xs[lk + 2][lr] = xa.z; xs[lk + 3][lr] = xa.w;
    xs[lk + 4][lr] = xb.x; xs[lk + 5][lr] = xb.y; xs[lk + 6][lr] = xb.z; xs[lk + 7][lr] = xb.w;

    const float* wsrc = W + (size_t)k0 * BN + tid * 16;
    float* wdst = &ws[0][0] + tid * 16;
#pragma unroll
    for (int i = 0; i < 4; i++) ((float4*)wdst)[i] = ((const float4*)wsrc)[i];
    __syncthreads();

#pragma unroll
    for (int kk = 0; kk < BK; kk++) {
      float4 a0 = *(const float4*)&xs[kk][rg * 8];
      float4 a1 = *(const float4*)&xs[kk][rg * 8 + 4];
      float4 b  = *(const float4*)&ws[kk][cg * 4];
      float av[8] = {a0.x, a0.y, a0.z, a0.w, a1.x, a1.y, a1.z, a1.w};
      float bv[4] = {b.x, b.y, b.z, b.w};
#pragma unroll
      for (int r = 0; r < 8; r++)
#pragma unroll
        for (int c = 0; c < 4; c++) acc[r][c] = fmaf(av[r], bv[c], acc[r][c]);
    }
    __syncthreads();
  }

#pragma unroll
  for (int r = 0; r < 8; r++) {
    int row = m0 + rg * 8 + r;
    if (row < N_NODES) {
      float4 o = make_float4(acc[r][0], acc[r][1], acc[r][2], acc[r][3]);
      *(float4*)(h1 + (size_t)row * C_HID + cg * 4) = o;
    }
  }
}

// ---------------------------------------------------------------------------
// att1: per-node attention logits  a_src[n] = h1[n].att_src, a_dst likewise
// one wave per node
// ---------------------------------------------------------------------------
__global__ __launch_bounds__(256) void att1_kernel(const float* __restrict__ h1,
                                                   const float* __restrict__ att_src,
                                                   const float* __restrict__ att_dst,
                                                   float* __restrict__ a_src,
                                                   float* __restrict__ a_dst) {
  const int wave = threadIdx.x >> 6;
  const int lane = threadIdx.x & 63;
  const int n = blockIdx.x * 4 + wave;
  if (n >= N_NODES) return;
  float h0  = h1[(size_t)n * C_HID + lane];
  float h64 = h1[(size_t)n * C_HID + 64 + lane];
  float s = h0 * att_src[lane] + h64 * att_src[64 + lane];
  float d = h0 * att_dst[lane] + h64 * att_dst[64 + lane];
#pragma unroll
  for (int m = 32; m >= 1; m >>= 1) {
    s += __shfl_xor(s, m, 64);
    d += __shfl_xor(d, m, 64);
  }
  if (lane == 0) { a_src[n] = s; a_dst[n] = d; }
}

// ---------------------------------------------------------------------------
// CSR build: histogram of dst, exclusive scan, bucket src indices
// ---------------------------------------------------------------------------
__global__ void deg_kernel(const int* __restrict__ ei, int* __restrict__ deg) {
  int e = blockIdx.x * blockDim.x + threadIdx.x;
  if (e >= E_TOT) return;
  int dst = (e < N_EDGES) ? ei[N_EDGES + e] : (e - N_EDGES);
  atomicAdd(&deg[dst], 1);
}

#define SCAN_T 1024
__global__ __launch_bounds__(SCAN_T) void scan_kernel(const int* __restrict__ deg,
                                                      int* __restrict__ rowptr,
                                                      int* __restrict__ cursor, int n) {
  __shared__ int buf[SCAN_T];
  __shared__ int carry_s;
  const int tid = threadIdx.x;
  if (tid == 0) carry_s = 0;
  __syncthreads();
  for (int base = 0; base < n; base += SCAN_T) {
    int i = base + tid;
    int v = (i < n) ? deg[i] : 0;
    buf[tid] = v;
    __syncthreads();
    int sum = v;
    for (int off = 1; off < SCAN_T; off <<= 1) {
      int t = (tid >= off) ? buf[tid - off] : 0;
      __syncthreads();
      sum += t;
      buf[tid] = sum;
      __syncthreads();
    }
    int c = carry_s;
    if (i < n) { rowptr[i] = c + sum - v; cursor[i] = c + sum - v; }
    __syncthreads();
    if (tid == SCAN_T - 1) carry_s = c + sum;
    __syncthreads();
  }
  if (tid == 0) rowptr[n] = carry_s;
}

__global__ void bucket_kernel(const int* __restrict__ ei, int* __restrict__ cursor,
                              int* __restrict__ esrc) {
  int e = blockIdx.x * blockDim.x + threadIdx.x;
  if (e >= E_TOT) return;
  int src, dst;
  if (e < N_EDGES) { src = ei[e]; dst = ei[N_EDGES + e]; }
  else             { src = dst = e - N_EDGES; }
  int slot = atomicAdd(&cursor[dst], 1);
  esrc[slot] = src;
}

// ---------------------------------------------------------------------------
// agg1: layer-1 segment softmax + aggregation, one wave per node.
// Epilogue fuses: +bias1, ReLU, layer-2 linear (128->6), layer-2 att dots.
// ---------------------------------------------------------------------------
__global__ __launch_bounds__(256) void agg1_kernel(const float* __restrict__ h1,
    const float* __restrict__ a_src, const float* __restrict__ a_dst,
    const int* __restrict__ rowptr, const int* __restrict__ esrc,
    const float* __restrict__ bias1, const float* __restrict__ W2,
    const float* __restrict__ att_src2, const float* __restrict__ att_dst2,
    float* __restrict__ h2, float* __restrict__ as2, float* __restrict__ ad2) {
  const int wave = threadIdx.x >> 6;
  const int lane = threadIdx.x & 63;
  const int n = blockIdx.x * 4 + wave;
  if (n >= N_NODES) return;

  const int start = rowptr[n], end = rowptr[n + 1];
  const float adst = a_dst[n];

  // pass 1: segment max  (every node has >=1 edge via self-loop)
  float m = -1e30f;
  for (int j = start + lane; j < end; j += 64)
    m = fmaxf(m, leaky(a_src[esrc[j]] + adst));
#pragma unroll
  for (int o = 32; o >= 1; o >>= 1) m = fmaxf(m, __shfl_xor(m, o, 64));

  // pass 2: denom
  float dsum = 0.f;
  for (int j = start + lane; j < end; j += 64)
    dsum += __expf(leaky(a_src[esrc[j]] + adst) - m);
#pragma unroll
  for (int o = 32; o >= 1; o >>= 1) dsum += __shfl_xor(dsum, o, 64);
  const float inv = 1.f / (dsum + 1e-16f);

  // pass 3: weighted gather-accumulate; lane owns channels (2*lane, 2*lane+1)
  float2 acc = make_float2(0.f, 0.f);
  for (int j = start; j < end; j++) {
    int s = esrc[j];
    float w = __expf(leaky(a_src[s] + adst) - m) * inv;
    float2 hv = *(const float2*)(h1 + (size_t)s * C_HID + 2 * lane);
    acc.x = fmaf(w, hv.x, acc.x);
    acc.y = fmaf(w, hv.y, acc.y);
  }

  // epilogue: relu(acc + bias1) -> h2row = h2in @ W2 (128x6) -> att2 dots
  float2 b = *(const float2*)(bias1 + 2 * lane);
  float v0 = fmaxf(acc.x + b.x, 0.f);
  float v1 = fmaxf(acc.y + b.y, 0.f);
  float p[6];
  const float* w2a = W2 + (size_t)(2 * lane) * 6;
#pragma unroll
  for (int o = 0; o < 6; o++) p[o] = v0 * w2a[o] + v1 * w2a[6 + o];
#pragma unroll
  for (int o = 0; o < 6; o++)
#pragma unroll
    for (int msk = 32; msk >= 1; msk >>= 1) p[o] += __shfl_xor(p[o], msk, 64);

  if (lane == 0) {
#pragma unroll
    for (int o = 0; o < 6; o++) h2[(size_t)n * 8 + o] = p[o];
#pragma unroll
    for (int h = 0; h < HEADS2; h++) {
      as2[n * 4 + h] = p[2 * h] * att_src2[2 * h] + p[2 * h + 1] * att_src2[2 * h + 1];
      ad2[n * 4 + h] = p[2 * h] * att_dst2[2 * h] + p[2 * h + 1] * att_dst2[2 * h + 1];
    }
  }
}

// ---------------------------------------------------------------------------
// agg2: layer-2 softmax+aggregate, one lane per node (online softmax, 3 heads)
// out[n] = mean over heads + bias2
// ---------------------------------------------------------------------------
__global__ __launch_bounds__(256) void agg2_kernel(const float* __restrict__ h2,
    const float* __restrict__ as2, const float* __restrict__ ad2,
    const int* __restrict__ rowptr, const int* __restrict__ esrc,
    const float* __restrict__ bias2, float* __restrict__ out) {
  int n = blockIdx.x * blockDim.x + threadIdx.x;
  if (n >= N_NODES) return;
  float4 adv = *(const float4*)(ad2 + n * 4);
  float ad[3] = {adv.x, adv.y, adv.z};
  float m[3] = {-1e30f, -1e30f, -1e30f};
  float d[3] = {0.f, 0.f, 0.f};
  float acc[6] = {0.f, 0.f, 0.f, 0.f, 0.f, 0.f};
  const int end = rowptr[n + 1];
  for (int j = rowptr[n]; j < end; j++) {
    int s = esrc[j];
    float4 asv = *(const float4*)(as2 + s * 4);
    float as_[3] = {asv.x, asv.y, asv.z};
    float4 hlo = *(const float4*)(h2 + (size_t)s * 8);
    float4 hhi = *(const float4*)(h2 + (size_t)s * 8 + 4);
    float hv[6] = {hlo.x, hlo.y, hlo.z, hlo.w, hhi.x, hhi.y};
#pragma unroll
    for (int h = 0; h < 3; h++) {
      float e  = leaky(as_[h] + ad[h]);
      float nm = fmaxf(m[h], e);
      float s1 = __expf(m[h] - nm);
      float s2 = __expf(e - nm);
      d[h] = d[h] * s1 + s2;
      acc[2 * h]     = acc[2 * h] * s1     + s2 * hv[2 * h];
      acc[2 * h + 1] = acc[2 * h + 1] * s1 + s2 * hv[2 * h + 1];
      m[h] = nm;
    }
  }
  float o0 = 0.f, o1 = 0.f;
#pragma unroll
  for (int h = 0; h < 3; h++) {
    float invd = 1.f / (d[h] + 1e-16f);
    o0 += acc[2 * h] * invd;
    o1 += acc[2 * h + 1] * invd;
  }
  out[n * 2 + 0] = o0 * (1.f / 3.f) + bias2[0];
  out[n * 2 + 1] = o1 * (1.f / 3.f) + bias2[1];
}

// ---------------------------------------------------------------------------
extern "C" void kernel_launch(void* const* d_in, const int* in_sizes, int n_in,
                              void* d_out, int out_size, void* d_ws, size_t ws_size,
                              hipStream_t stream) {
  const float* x        = (const float*)d_in[0];
  const int*   ei       = (const int*)d_in[1];
  const float* W1       = (const float*)d_in[2];
  const float* att_src1 = (const float*)d_in[3];
  const float* att_dst1 = (const float*)d_in[4];
  const float* bias1    = (const float*)d_in[5];
  const float* W2       = (const float*)d_in[6];
  const float* att_src2 = (const float*)d_in[7];
  const float* att_dst2 = (const float*)d_in[8];
  const float* bias2    = (const float*)d_in[9];
  float* out = (float*)d_out;

  char* w = (char*)d_ws;
  auto alloc = [&](size_t bytes) {
    char* p = w;
    w += (bytes + 255) & ~(size_t)255;
    return p;
  };
  float* h1     = (float*)alloc((size_t)N_NODES * C_HID * 4);   // 25.6 MB
  float* a_src1 = (float*)alloc((size_t)N_NODES * 4);
  float* a_dst1 = (float*)alloc((size_t)N_NODES * 4);
  int*   deg    = (int*)alloc((size_t)N_NODES * 4);
  int*   rowptr = (int*)alloc((size_t)(N_NODES + 1) * 4);
  int*   cursor = (int*)alloc((size_t)N_NODES * 4);
  int*   esrc   = (int*)alloc((size_t)E_TOT * 4);               // 3.4 MB
  float* h2     = (float*)alloc((size_t)N_NODES * 8 * 4);       // padded stride 8
  float* as2    = (float*)alloc((size_t)N_NODES * 4 * 4);       // padded stride 4
  float* ad2    = (float*)alloc((size_t)N_NODES * 4 * 4);

  hipMemsetAsync(deg, 0, (size_t)N_NODES * 4, stream);

  lin1_kernel<<<(N_NODES + BM - 1) / BM, 256, 0, stream>>>(x, W1, h1);
  att1_kernel<<<(N_NODES + 3) / 4, 256, 0, stream>>>(h1, att_src1, att_dst1, a_src1, a_dst1);
  deg_kernel<<<(E_TOT + 255) / 256, 256, 0, stream>>>(ei, deg);
  scan_kernel<<<1, SCAN_T, 0, stream>>>(deg, rowptr, cursor, N_NODES);
  bucket_kernel<<<(E_TOT + 255) / 256, 256, 0, stream>>>(ei, cursor, esrc);
  agg1_kernel<<<(N_NODES + 3) / 4, 256, 0, stream>>>(h1, a_src1, a_dst1, rowptr, esrc,
                                                     bias1, W2, att_src2, att_dst2,
                                                     h2, as2, ad2);
  agg2_kernel<<<(N_NODES + 255) / 256, 256, 0, stream>>>(h2, as2, ad2, rowptr, esrc,
                                                         bias2, out);
}

// Round 2
// 412.327 us; speedup vs baseline: 1.3215x; 1.3215x over previous
//
#include <hip/hip_runtime.h>

#define N_NODES 50000
#define N_EDGES 800000
#define E_TOT   850000   /* N_EDGES + N_NODES self-loops */
#define C_IN    512
#define C_HID   128
#define NEG     0.2f

typedef __attribute__((ext_vector_type(8))) short short8;
typedef __attribute__((ext_vector_type(4))) float f32x4;

__device__ __forceinline__ float leaky(float x) { return x > 0.f ? x : NEG * x; }

// round-to-nearest-even fp32 -> bf16 (as raw ushort)
__device__ __forceinline__ unsigned short f2bf(float f) {
  unsigned u = __float_as_uint(f);
  u += 0x7fff + ((u >> 16) & 1);
  return (unsigned short)(u >> 16);
}
__device__ __forceinline__ float bf2f(unsigned short h) {
  return __uint_as_float(((unsigned)h) << 16);
}

// ---------------------------------------------------------------------------
// prep: W1 -> transposed bf16 hi/lo (W1T[c][k]); v1s = W1 @ att_src1, v1d = W1 @ att_dst1
// ---------------------------------------------------------------------------
__global__ __launch_bounds__(256) void prep_kernel(const float* __restrict__ W1,
    const float* __restrict__ as1, const float* __restrict__ ad1,
    unsigned short* __restrict__ Wh, unsigned short* __restrict__ Wl,
    float* __restrict__ v1s, float* __restrict__ v1d) {
  int k = blockIdx.x * 256 + threadIdx.x;
  if (k >= C_IN) return;
  float s = 0.f, d = 0.f;
  for (int c = 0; c < C_HID; c++) {
    float w = W1[(size_t)k * C_HID + c];
    unsigned short hi = f2bf(w);
    Wh[(size_t)c * C_IN + k] = hi;
    Wl[(size_t)c * C_IN + k] = f2bf(w - bf2f(hi));
    s += w * as1[c];
    d += w * ad1[c];
  }
  v1s[k] = s;
  v1d[k] = d;
}

// ---------------------------------------------------------------------------
// lin1: h1 = x @ W1 via bf16x3 MFMA (hi*Whi + hi*Wlo + lo*Whi), fused a_src/a_dst
// block tile 128x128, BK=32, 256 threads = 4 waves, wave owns 32 rows x 128 cols
// ---------------------------------------------------------------------------
__global__ __launch_bounds__(256) void lin1_kernel(const float* __restrict__ x,
    const unsigned short* __restrict__ Wh, const unsigned short* __restrict__ Wl,
    const float* __restrict__ v1s, const float* __restrict__ v1d,
    float* __restrict__ h1, float* __restrict__ a_src, float* __restrict__ a_dst) {
  // row stride 40 bf16 (80 B): frag reads land 2-way bank aliased (free on CDNA4)
  __shared__ __attribute__((aligned(16))) unsigned short Ah[128][40];
  __shared__ __attribute__((aligned(16))) unsigned short Al[128][40];
  __shared__ __attribute__((aligned(16))) unsigned short Bh[128][40];
  __shared__ __attribute__((aligned(16))) unsigned short Bl[128][40];

  const int tid  = threadIdx.x;
  const int lane = tid & 63, wv = tid >> 6;
  const int m0   = blockIdx.x * 128;

  // A staging: thread covers rows arow+32i (i=0..3), k-quad kq (4 floats)
  const int arow = tid >> 3, kq = tid & 7;
  const float* xp[4];
#pragma unroll
  for (int i = 0; i < 4; i++) {
    int r = m0 + arow + 32 * i;
    if (r >= N_NODES) r = N_NODES - 1;   // clamp; all stores guarded
    xp[i] = x + (size_t)r * C_IN + kq * 4;
  }
  // B staging: thread covers col bcol, k-half bhalf (16 bf16 = 32 B)
  const int bcol = tid >> 1, bhalf = tid & 1;
  const unsigned short* whp = Wh + (size_t)bcol * C_IN + bhalf * 16;
  const unsigned short* wlp = Wl + (size_t)bcol * C_IN + bhalf * 16;

  f32x4 acc[2][8];
#pragma unroll
  for (int a = 0; a < 2; a++)
#pragma unroll
    for (int b = 0; b < 8; b++) acc[a][b] = (f32x4)0.f;
  float ps[4] = {0, 0, 0, 0}, pd[4] = {0, 0, 0, 0};

  const int q = lane >> 4, l15 = lane & 15;

  for (int k0 = 0; k0 < C_IN; k0 += 32) {
    // ---- stage A (fp32 -> bf16 hi/lo) + fused attention-dot partials ----
    float4 vs = *(const float4*)(v1s + k0 + kq * 4);
    float4 vd = *(const float4*)(v1d + k0 + kq * 4);
#pragma unroll
    for (int i = 0; i < 4; i++) {
      float4 xv = *(const float4*)(xp[i] + k0);
      ps[i] += xv.x * vs.x + xv.y * vs.y + xv.z * vs.z + xv.w * vs.w;
      pd[i] += xv.x * vd.x + xv.y * vd.y + xv.z * vd.z + xv.w * vd.w;
      unsigned short h0 = f2bf(xv.x), h1_ = f2bf(xv.y), h2_ = f2bf(xv.z), h3 = f2bf(xv.w);
      ushort4 hv = make_ushort4(h0, h1_, h2_, h3);
      ushort4 lv = make_ushort4(f2bf(xv.x - bf2f(h0)),  f2bf(xv.y - bf2f(h1_)),
                                f2bf(xv.z - bf2f(h2_)), f2bf(xv.w - bf2f(h3)));
      int lrow = arow + 32 * i;
      *(ushort4*)&Ah[lrow][kq * 4] = hv;
      *(ushort4*)&Al[lrow][kq * 4] = lv;
    }
    // ---- stage B (pre-converted bf16, pre-transposed) ----
    {
      const int4* sh = (const int4*)(whp + k0);
      const int4* sl = (const int4*)(wlp + k0);
      int4* dh = (int4*)&Bh[bcol][bhalf * 16];
      int4* dl = (int4*)&Bl[bcol][bhalf * 16];
      dh[0] = sh[0]; dh[1] = sh[1];
      dl[0] = sl[0]; dl[1] = sl[1];
    }
    __syncthreads();

    // ---- MFMA: 16 tiles x 3 products ----
    short8 ah0 = *(const short8*)&Ah[wv * 32 + l15][q * 8];
    short8 ah1 = *(const short8*)&Ah[wv * 32 + 16 + l15][q * 8];
    short8 al0 = *(const short8*)&Al[wv * 32 + l15][q * 8];
    short8 al1 = *(const short8*)&Al[wv * 32 + 16 + l15][q * 8];
#pragma unroll
    for (int t = 0; t < 8; t++) {
      short8 bh = *(const short8*)&Bh[t * 16 + l15][q * 8];
      short8 bl = *(const short8*)&Bl[t * 16 + l15][q * 8];
      acc[0][t] = __builtin_amdgcn_mfma_f32_16x16x32_bf16(ah0, bh, acc[0][t], 0, 0, 0);
      acc[0][t] = __builtin_amdgcn_mfma_f32_16x16x32_bf16(ah0, bl, acc[0][t], 0, 0, 0);
      acc[0][t] = __builtin_amdgcn_mfma_f32_16x16x32_bf16(al0, bh, acc[0][t], 0, 0, 0);
      acc[1][t] = __builtin_amdgcn_mfma_f32_16x16x32_bf16(ah1, bh, acc[1][t], 0, 0, 0);
      acc[1][t] = __builtin_amdgcn_mfma_f32_16x16x32_bf16(ah1, bl, acc[1][t], 0, 0, 0);
      acc[1][t] = __builtin_amdgcn_mfma_f32_16x16x32_bf16(al1, bh, acc[1][t], 0, 0, 0);
    }
    __syncthreads();
  }

  // ---- fused attention dots: reduce over the 8 threads sharing a row ----
#pragma unroll
  for (int i = 0; i < 4; i++) {
#pragma unroll
    for (int off = 1; off < 8; off <<= 1) {
      ps[i] += __shfl_xor(ps[i], off, 64);
      pd[i] += __shfl_xor(pd[i], off, 64);
    }
  }
  if ((tid & 7) == 0) {
#pragma unroll
    for (int i = 0; i < 4; i++) {
      int row = m0 + 32 * i + arow;
      if (row < N_NODES) { a_src[row] = ps[i]; a_dst[row] = pd[i]; }
    }
  }

  // ---- C store: C/D layout col=lane&15, row=(lane>>4)*4+reg ----
#pragma unroll
  for (int rt = 0; rt < 2; rt++) {
    int rbase = m0 + wv * 32 + rt * 16 + q * 4;
#pragma unroll
    for (int t = 0; t < 8; t++) {
#pragma unroll
      for (int ri = 0; ri < 4; ri++) {
        int row = rbase + ri;
        if (row < N_NODES) h1[(size_t)row * C_HID + t * 16 + l15] = acc[rt][t][ri];
      }
    }
  }
}

// ---------------------------------------------------------------------------
// CSR build
// ---------------------------------------------------------------------------
__global__ void init_deg_kernel(int* __restrict__ deg) {
  int n = blockIdx.x * blockDim.x + threadIdx.x;
  if (n < N_NODES) deg[n] = 1;   // self-loop
}

__global__ void deg_kernel(const int* __restrict__ ei, int* __restrict__ deg) {
  int e = blockIdx.x * blockDim.x + threadIdx.x;
  if (e >= N_EDGES) return;
  atomicAdd(&deg[ei[N_EDGES + e]], 1);
}

// single-block wave-shuffle scan: 1024 threads x 4 items, 3 barriers/chunk
__global__ __launch_bounds__(1024) void scan_kernel(const int* __restrict__ deg,
                                                    int* __restrict__ rowptr,
                                                    int* __restrict__ cursor) {
  __shared__ int wsum[16];
  const int tid = threadIdx.x, lane = tid & 63, wv = tid >> 6;
  int carry = 0;
  for (int base = 0; base < N_NODES; base += 4096) {
    int i0 = base + tid * 4;
    int4 v = make_int4(0, 0, 0, 0);
    if (i0 < N_NODES) v = *(const int4*)(deg + i0);   // N_NODES % 4 == 0
    int tsum = v.x + v.y + v.z + v.w;
    int sc = tsum;
#pragma unroll
    for (int off = 1; off < 64; off <<= 1) {
      int t = __shfl_up(sc, off, 64);
      if (lane >= off) sc += t;
    }
    if (lane == 63) wsum[wv] = sc;
    __syncthreads();
    if (wv == 0 && lane < 16) {
      int s = wsum[lane];
#pragma unroll
      for (int off = 1; off < 16; off <<= 1) {
        int t = __shfl_up(s, off, 64);
        if (lane >= off) s += t;
      }
      wsum[lane] = s;
    }
    __syncthreads();
    int ex = carry + (wv ? wsum[wv - 1] : 0) + sc - tsum;
    if (i0 < N_NODES) {
      int4 o = make_int4(ex, ex + v.x, ex + v.x + v.y, ex + v.x + v.y + v.z);
      *(int4*)(rowptr + i0) = o;
      *(int4*)(cursor + i0) = o;
    }
    carry += wsum[15];
    __syncthreads();
  }
  if (tid == 0) rowptr[N_NODES] = carry;
}

__global__ void bucket_kernel(const int* __restrict__ ei, int* __restrict__ cursor,
                              int* __restrict__ esrc) {
  int e = blockIdx.x * blockDim.x + threadIdx.x;
  if (e >= E_TOT) return;
  int src, dst;
  if (e < N_EDGES) { src = ei[e]; dst = ei[N_EDGES + e]; }
  else             { src = dst = e - N_EDGES; }
  int slot = atomicAdd(&cursor[dst], 1);
  esrc[slot] = src;
}

// ---------------------------------------------------------------------------
// agg1: single-pass unnormalized softmax-aggregate (no max shift: |logit| < ~15),
// wave per node, lane owns channels (2*lane, 2*lane+1).
// Epilogue fuses +bias1, ReLU, layer-2 linear (128->6), layer-2 att dots.
// ---------------------------------------------------------------------------
__global__ __launch_bounds__(256) void agg1_kernel(const float* __restrict__ h1,
    const float* __restrict__ a_src, const float* __restrict__ a_dst,
    const int* __restrict__ rowptr, const int* __restrict__ esrc,
    const float* __restrict__ bias1, const float* __restrict__ W2,
    const float* __restrict__ as2w, const float* __restrict__ ad2w,
    float* __restrict__ h2, float* __restrict__ as2, float* __restrict__ ad2) {
  const int wv = threadIdx.x >> 6, lane = threadIdx.x & 63;
  const int n = blockIdx.x * 4 + wv;
  if (n >= N_NODES) return;
  const int start = rowptr[n], end = rowptr[n + 1];
  const float adst = a_dst[n];

  float2 acc = make_float2(0.f, 0.f);
  float dsum = 0.f;
  int j = start;
  for (; j + 1 < end; j += 2) {     // unroll x2: two loads in flight
    int s0 = esrc[j], s1 = esrc[j + 1];
    float as0 = a_src[s0], as1 = a_src[s1];
    float2 v0 = *(const float2*)(h1 + (size_t)s0 * C_HID + 2 * lane);
    float2 v1 = *(const float2*)(h1 + (size_t)s1 * C_HID + 2 * lane);
    float e0 = __expf(leaky(as0 + adst));
    float e1 = __expf(leaky(as1 + adst));
    dsum += e0 + e1;
    acc.x += e0 * v0.x + e1 * v1.x;
    acc.y += e0 * v0.y + e1 * v1.y;
  }
  if (j < end) {
    int s0 = esrc[j];
    float2 v0 = *(const float2*)(h1 + (size_t)s0 * C_HID + 2 * lane);
    float e0 = __expf(leaky(a_src[s0] + adst));
    dsum += e0;
    acc.x += e0 * v0.x;
    acc.y += e0 * v0.y;
  }
  const float inv = 1.f / dsum;     // >= exp(-~15) > 0 via self-loop

  float2 b = *(const float2*)(bias1 + 2 * lane);
  float u0 = fmaxf(acc.x * inv + b.x, 0.f);
  float u1 = fmaxf(acc.y * inv + b.y, 0.f);
  float p[6];
  const float* w2a = W2 + (size_t)(2 * lane) * 6;
#pragma unroll
  for (int o = 0; o < 6; o++) p[o] = u0 * w2a[o] + u1 * w2a[6 + o];
#pragma unroll
  for (int o = 0; o < 6; o++)
#pragma unroll
    for (int msk = 32; msk >= 1; msk >>= 1) p[o] += __shfl_xor(p[o], msk, 64);

  if (lane == 0) {
#pragma unroll
    for (int o = 0; o < 6; o++) h2[(size_t)n * 8 + o] = p[o];
#pragma unroll
    for (int h = 0; h < 3; h++) {
      as2[n * 4 + h] = p[2 * h] * as2w[2 * h] + p[2 * h + 1] * as2w[2 * h + 1];
      ad2[n * 4 + h] = p[2 * h] * ad2w[2 * h] + p[2 * h + 1] * ad2w[2 * h + 1];
    }
  }
}

// ---------------------------------------------------------------------------
// agg2: wave per node, lanes strided over edges, single pass (no max shift),
// 9 cross-lane reductions at the end. out = mean over heads + bias2.
// ---------------------------------------------------------------------------
__global__ __launch_bounds__(256) void agg2_kernel(const float* __restrict__ h2,
    const float* __restrict__ as2, const float* __restrict__ ad2,
    const int* __restrict__ rowptr, const int* __restrict__ esrc,
    const float* __restrict__ bias2, float* __restrict__ out) {
  const int wv = threadIdx.x >> 6, lane = threadIdx.x & 63;
  const int n = blockIdx.x * 4 + wv;
  if (n >= N_NODES) return;
  const int start = rowptr[n], end = rowptr[n + 1];
  const float4 adv = *(const float4*)(ad2 + (size_t)n * 4);

  float d0 = 0.f, d1 = 0.f, d2 = 0.f;
  float a0 = 0.f, a1 = 0.f, a2 = 0.f, a3 = 0.f, a4 = 0.f, a5 = 0.f;
  for (int j = start + lane; j < end; j += 64) {
    int s = esrc[j];
    float4 asv = *(const float4*)(as2 + (size_t)s * 4);
    float4 hlo = *(const float4*)(h2 + (size_t)s * 8);
    float2 hhi = *(const float2*)(h2 + (size_t)s * 8 + 4);
    float e0 = __expf(leaky(asv.x + adv.x));
    float e1 = __expf(leaky(asv.y + adv.y));
    float e2 = __expf(leaky(asv.z + adv.z));
    d0 += e0; d1 += e1; d2 += e2;
    a0 += e0 * hlo.x; a1 += e0 * hlo.y;
    a2 += e1 * hlo.z; a3 += e1 * hlo.w;
    a4 += e2 * hhi.x; a5 += e2 * hhi.y;
  }
#pragma unroll
  for (int m = 32; m >= 1; m >>= 1) {
    d0 += __shfl_xor(d0, m, 64); d1 += __shfl_xor(d1, m, 64); d2 += __shfl_xor(d2, m, 64);
    a0 += __shfl_xor(a0, m, 64); a1 += __shfl_xor(a1, m, 64); a2 += __shfl_xor(a2, m, 64);
    a3 += __shfl_xor(a3, m, 64); a4 += __shfl_xor(a4, m, 64); a5 += __shfl_xor(a5, m, 64);
  }
  if (lane == 0) {
    float o0 = (a0 / d0 + a2 / d1 + a4 / d2) * (1.f / 3.f) + bias2[0];
    float o1 = (a1 / d0 + a3 / d1 + a5 / d2) * (1.f / 3.f) + bias2[1];
    *(float2*)(out + (size_t)n * 2) = make_float2(o0, o1);
  }
}

// ---------------------------------------------------------------------------
extern "C" void kernel_launch(void* const* d_in, const int* in_sizes, int n_in,
                              void* d_out, int out_size, void* d_ws, size_t ws_size,
                              hipStream_t stream) {
  const float* x        = (const float*)d_in[0];
  const int*   ei       = (const int*)d_in[1];
  const float* W1       = (const float*)d_in[2];
  const float* att_src1 = (const float*)d_in[3];
  const float* att_dst1 = (const float*)d_in[4];
  const float* bias1    = (const float*)d_in[5];
  const float* W2       = (const float*)d_in[6];
  const float* att_src2 = (const float*)d_in[7];
  const float* att_dst2 = (const float*)d_in[8];
  const float* bias2    = (const float*)d_in[9];
  float* out = (float*)d_out;

  char* w = (char*)d_ws;
  auto alloc = [&](size_t bytes) {
    char* p = w;
    w += (bytes + 255) & ~(size_t)255;
    return p;
  };
  float*          h1     = (float*)alloc((size_t)N_NODES * C_HID * 4);
  unsigned short* W1Th   = (unsigned short*)alloc((size_t)C_IN * C_HID * 2);
  unsigned short* W1Tl   = (unsigned short*)alloc((size_t)C_IN * C_HID * 2);
  float*          v1s    = (float*)alloc((size_t)C_IN * 4);
  float*          v1d    = (float*)alloc((size_t)C_IN * 4);
  float*          a_src1 = (float*)alloc((size_t)N_NODES * 4);
  float*          a_dst1 = (float*)alloc((size_t)N_NODES * 4);
  int*            deg    = (int*)alloc((size_t)N_NODES * 4);
  int*            rowptr = (int*)alloc((size_t)(N_NODES + 4) * 4);
  int*            cursor = (int*)alloc((size_t)N_NODES * 4);
  int*            esrc   = (int*)alloc((size_t)E_TOT * 4);
  float*          h2     = (float*)alloc((size_t)N_NODES * 8 * 4);
  float*          as2    = (float*)alloc((size_t)N_NODES * 4 * 4);
  float*          ad2    = (float*)alloc((size_t)N_NODES * 4 * 4);

  prep_kernel<<<(C_IN + 255) / 256, 256, 0, stream>>>(W1, att_src1, att_dst1,
                                                      W1Th, W1Tl, v1s, v1d);
  lin1_kernel<<<(N_NODES + 127) / 128, 256, 0, stream>>>(x, W1Th, W1Tl, v1s, v1d,
                                                         h1, a_src1, a_dst1);
  init_deg_kernel<<<(N_NODES + 255) / 256, 256, 0, stream>>>(deg);
  deg_kernel<<<(N_EDGES + 255) / 256, 256, 0, stream>>>(ei, deg);
  scan_kernel<<<1, 1024, 0, stream>>>(deg, rowptr, cursor);
  bucket_kernel<<<(E_TOT + 255) / 256, 256, 0, stream>>>(ei, cursor, esrc);
  agg1_kernel<<<(N_NODES + 3) / 4, 256, 0, stream>>>(h1, a_src1, a_dst1, rowptr, esrc,
                                                     bias1, W2, att_src2, att_dst2,
                                                     h2, as2, ad2);
  agg2_kernel<<<(N_NODES + 3) / 4, 256, 0, stream>>>(h2, as2, ad2, rowptr, esrc,
                                                     bias2, out);
}

// Round 4
// 373.633 us; speedup vs baseline: 1.4583x; 1.1036x over previous
//
#include <hip/hip_runtime.h>

#define N_NODES 50000
#define N_EDGES 800000
#define E_TOT   850000   /* N_EDGES + N_NODES self-loops */
#define C_IN    512
#define C_HID   128
#define NEG     0.2f

typedef _Float16 f16x8 __attribute__((ext_vector_type(8)));
typedef __attribute__((ext_vector_type(4))) float f32x4;

__device__ __forceinline__ float leaky(float x) { return x > 0.f ? x : NEG * x; }

union U32H2 { unsigned u; _Float16 h[2]; float f; };

__device__ __forceinline__ unsigned short f2h(float f) {
  U32H2 c; c.h[0] = (_Float16)f; return (unsigned short)(c.u & 0xffff);
}

// pack two fp32 -> fp16x2 (RTZ hardware op) as raw u32
__device__ __forceinline__ unsigned pk2h(float a, float b) {
  union { __fp16 v __attribute__((ext_vector_type(2))); unsigned u; } c;
  c.v = __builtin_amdgcn_cvt_pkrtz(a, b);
  return c.u;
}

// ---------------------------------------------------------------------------
// prep_v: v1s[k] = sum_c W1[k,c]*att_src1[c], v1d likewise. Wave per k row.
// ---------------------------------------------------------------------------
__global__ __launch_bounds__(256) void prep_v_kernel(const float* __restrict__ W1,
    const float* __restrict__ as1, const float* __restrict__ ad1,
    float* __restrict__ v1s, float* __restrict__ v1d) {
  const int wv = threadIdx.x >> 6, lane = threadIdx.x & 63;
  const int k = blockIdx.x * 4 + wv;
  if (k >= C_IN) return;
  float2 w = *(const float2*)(W1 + (size_t)k * C_HID + 2 * lane);
  float2 a = *(const float2*)(as1 + 2 * lane);
  float2 d = *(const float2*)(ad1 + 2 * lane);
  float s = w.x * a.x + w.y * a.y;
  float t = w.x * d.x + w.y * d.y;
#pragma unroll
  for (int m = 32; m >= 1; m >>= 1) {
    s += __shfl_xor(s, m, 64);
    t += __shfl_xor(t, m, 64);
  }
  if (lane == 0) { v1s[k] = s; v1d[k] = t; }
}

// ---------------------------------------------------------------------------
// prep_w: W1 [512][128] fp32 -> transposed fp16 hi/lo  Wh/Wl [128][512]
// thread = (c, k-chunk of 16)
// ---------------------------------------------------------------------------
__global__ __launch_bounds__(256) void prep_w_kernel(const float* __restrict__ W1,
    unsigned short* __restrict__ Wh, unsigned short* __restrict__ Wl) {
  int t = blockIdx.x * 256 + threadIdx.x;          // 4096 threads
  int c = t >> 5, k0 = (t & 31) * 16;
  if (c >= C_HID) return;
#pragma unroll
  for (int i = 0; i < 16; i++) {
    float w = W1[(size_t)(k0 + i) * C_HID + c];
    _Float16 hi = (_Float16)w;                     // RNE
    _Float16 lo = (_Float16)(w - (float)hi);
    U32H2 ch; ch.h[0] = hi;
    U32H2 cl; cl.h[0] = lo;
    Wh[(size_t)c * C_IN + k0 + i] = (unsigned short)(ch.u & 0xffff);
    Wl[(size_t)c * C_IN + k0 + i] = (unsigned short)(cl.u & 0xffff);
  }
}

// ---------------------------------------------------------------------------
// lin1: h1 = x @ W1 via fp16 MFMA (x_h*W_hi + x_h*W_lo), fused fp32 a_src/a_dst
// block tile 128x128, BK=32, 256 threads = 4 waves. h1 stored as fp16.
// ---------------------------------------------------------------------------
__global__ __launch_bounds__(256) void lin1_kernel(const float* __restrict__ x,
    const unsigned short* __restrict__ Wh, const unsigned short* __restrict__ Wl,
    const float* __restrict__ v1s, const float* __restrict__ v1d,
    unsigned short* __restrict__ h1u, float* __restrict__ a_src, float* __restrict__ a_dst) {
  __shared__ __attribute__((aligned(16))) unsigned short As[128][40];
  __shared__ __attribute__((aligned(16))) unsigned short Bh[128][40];
  __shared__ __attribute__((aligned(16))) unsigned short Bl[128][40];

  const int tid  = threadIdx.x;
  const int lane = tid & 63, wv = tid >> 6;
  const int m0   = blockIdx.x * 128;

  const int arow = tid >> 3, kq = tid & 7;         // A staging: 4 rows x float4
  const float* xp[4];
#pragma unroll
  for (int i = 0; i < 4; i++) {
    int r = m0 + arow + 32 * i;
    if (r >= N_NODES) r = N_NODES - 1;             // clamp; stores guarded
    xp[i] = x + (size_t)r * C_IN + kq * 4;
  }
  const int bcol = tid >> 1, bhalf = tid & 1;      // B staging
  const unsigned short* whp = Wh + (size_t)bcol * C_IN + bhalf * 16;
  const unsigned short* wlp = Wl + (size_t)bcol * C_IN + bhalf * 16;

  f32x4 acc[2][8];
#pragma unroll
  for (int a = 0; a < 2; a++)
#pragma unroll
    for (int b = 0; b < 8; b++) acc[a][b] = (f32x4)0.f;
  float ps[4] = {0, 0, 0, 0}, pd[4] = {0, 0, 0, 0};

  const int q = lane >> 4, l15 = lane & 15;

  for (int k0 = 0; k0 < C_IN; k0 += 32) {
    float4 vs = *(const float4*)(v1s + k0 + kq * 4);
    float4 vd = *(const float4*)(v1d + k0 + kq * 4);
#pragma unroll
    for (int i = 0; i < 4; i++) {
      float4 xv = *(const float4*)(xp[i] + k0);
      ps[i] += xv.x * vs.x + xv.y * vs.y + xv.z * vs.z + xv.w * vs.w;
      pd[i] += xv.x * vd.x + xv.y * vd.y + xv.z * vd.z + xv.w * vd.w;
      *(uint2*)&As[arow + 32 * i][kq * 4] = make_uint2(pk2h(xv.x, xv.y), pk2h(xv.z, xv.w));
    }
    {
      const int4* sh = (const int4*)(whp + k0);
      const int4* sl = (const int4*)(wlp + k0);
      int4* dh = (int4*)&Bh[bcol][bhalf * 16];
      int4* dl = (int4*)&Bl[bcol][bhalf * 16];
      dh[0] = sh[0]; dh[1] = sh[1];
      dl[0] = sl[0]; dl[1] = sl[1];
    }
    __syncthreads();

    f16x8 a0 = *(const f16x8*)&As[wv * 32 + l15][q * 8];
    f16x8 a1 = *(const f16x8*)&As[wv * 32 + 16 + l15][q * 8];
#pragma unroll
    for (int t = 0; t < 8; t++) {
      f16x8 bh = *(const f16x8*)&Bh[t * 16 + l15][q * 8];
      f16x8 bl = *(const f16x8*)&Bl[t * 16 + l15][q * 8];
      acc[0][t] = __builtin_amdgcn_mfma_f32_16x16x32_f16(a0, bh, acc[0][t], 0, 0, 0);
      acc[0][t] = __builtin_amdgcn_mfma_f32_16x16x32_f16(a0, bl, acc[0][t], 0, 0, 0);
      acc[1][t] = __builtin_amdgcn_mfma_f32_16x16x32_f16(a1, bh, acc[1][t], 0, 0, 0);
      acc[1][t] = __builtin_amdgcn_mfma_f32_16x16x32_f16(a1, bl, acc[1][t], 0, 0, 0);
    }
    __syncthreads();
  }

  // fused attention dots: reduce over the 8 threads sharing a row
#pragma unroll
  for (int i = 0; i < 4; i++) {
#pragma unroll
    for (int off = 1; off < 8; off <<= 1) {
      ps[i] += __shfl_xor(ps[i], off, 64);
      pd[i] += __shfl_xor(pd[i], off, 64);
    }
  }
  if ((tid & 7) == 0) {
#pragma unroll
    for (int i = 0; i < 4; i++) {
      int row = m0 + 32 * i + arow;
      if (row < N_NODES) { a_src[row] = ps[i]; a_dst[row] = pd[i]; }
    }
  }

  // C store (fp16): C/D layout col=lane&15, row=(lane>>4)*4+reg
#pragma unroll
  for (int rt = 0; rt < 2; rt++) {
    int rbase = m0 + wv * 32 + rt * 16 + q * 4;
#pragma unroll
    for (int t = 0; t < 8; t++) {
#pragma unroll
      for (int ri = 0; ri < 4; ri++) {
        int row = rbase + ri;
        if (row < N_NODES)
          h1u[(size_t)row * C_HID + t * 16 + l15] = f2h(acc[rt][t][ri]);
      }
    }
  }
}

// ---------------------------------------------------------------------------
// CSR build: deg histogram (atomics), single-block shuffle scan (+1 self-loop
// folded in), bucket with fused edge-weight exp(leaky(a_src+a_dst)).
// ---------------------------------------------------------------------------
__global__ void deg_kernel(const int* __restrict__ ei, int* __restrict__ deg) {
  int e = blockIdx.x * blockDim.x + threadIdx.x;
  if (e >= N_EDGES) return;
  atomicAdd(&deg[ei[N_EDGES + e]], 1);
}

__global__ __launch_bounds__(1024) void scan_kernel(const int* __restrict__ deg,
                                                    int* __restrict__ rowptr,
                                                    int* __restrict__ cursor) {
  __shared__ int wsum[16];
  const int tid = threadIdx.x, lane = tid & 63, wv = tid >> 6;
  int carry = 0;
  for (int base = 0; base < N_NODES; base += 4096) {
    int i0 = base + tid * 4;
    int4 v = make_int4(0, 0, 0, 0);
    if (i0 < N_NODES) {                             // N_NODES % 4 == 0
      v = *(const int4*)(deg + i0);
      v.x += 1; v.y += 1; v.z += 1; v.w += 1;       // self-loops
    }
    int tsum = v.x + v.y + v.z + v.w;
    int sc = tsum;
#pragma unroll
    for (int off = 1; off < 64; off <<= 1) {
      int t = __shfl_up(sc, off, 64);
      if (lane >= off) sc += t;
    }
    if (lane == 63) wsum[wv] = sc;
    __syncthreads();
    if (wv == 0 && lane < 16) {
      int s = wsum[lane];
#pragma unroll
      for (int off = 1; off < 16; off <<= 1) {
        int t = __shfl_up(s, off, 64);
        if (lane >= off) s += t;
      }
      wsum[lane] = s;
    }
    __syncthreads();
    int ex = carry + (wv ? wsum[wv - 1] : 0) + sc - tsum;
    if (i0 < N_NODES) {
      int4 o = make_int4(ex, ex + v.x, ex + v.x + v.y, ex + v.x + v.y + v.z);
      *(int4*)(rowptr + i0) = o;
      *(int4*)(cursor + i0) = o;
    }
    carry += wsum[15];
    __syncthreads();
  }
  if (tid == 0) rowptr[N_NODES] = carry;
}

__global__ void bucket_kernel(const int* __restrict__ ei, int* __restrict__ cursor,
                              const float* __restrict__ a_src, const float* __restrict__ a_dst,
                              int2* __restrict__ esw) {
  int e = blockIdx.x * blockDim.x + threadIdx.x;
  if (e >= E_TOT) return;
  int src, dst;
  if (e < N_EDGES) { src = ei[e]; dst = ei[N_EDGES + e]; }
  else             { src = dst = e - N_EDGES; }
  float w = __expf(leaky(a_src[src] + a_dst[dst]));
  int slot = atomicAdd(&cursor[dst], 1);
  U32H2 c; c.f = w;
  esw[slot] = make_int2(src, (int)c.u);
}

// ---------------------------------------------------------------------------
// agg1: wave per node; chunk-load 64 (src,w) pairs lane-strided, shfl-broadcast;
// only memory op per edge is the fp16 h1 gather. lane owns channels 2l,2l+1.
// Epilogue fuses +bias1, ReLU, layer-2 linear (128->6), layer-2 att dots.
// ---------------------------------------------------------------------------
__global__ __launch_bounds__(256) void agg1_kernel(const unsigned short* __restrict__ h1u,
    const int2* __restrict__ esw, const int* __restrict__ rowptr,
    const float* __restrict__ bias1, const float* __restrict__ W2,
    const float* __restrict__ as2w, const float* __restrict__ ad2w,
    float* __restrict__ h2, float* __restrict__ as2, float* __restrict__ ad2) {
  const int wv = threadIdx.x >> 6, lane = threadIdx.x & 63;
  const int n = blockIdx.x * 4 + wv;
  if (n >= N_NODES) return;
  const int start = rowptr[n], end = rowptr[n + 1];

  float2 acc = make_float2(0.f, 0.f);
  float wsum = 0.f;
  for (int base = start; base < end; base += 64) {
    int idx = base + lane;
    int sreg = 0; float wreg = 0.f;
    if (idx < end) {
      int2 sv = esw[idx];
      sreg = sv.x;
      U32H2 c; c.u = (unsigned)sv.y;
      wreg = c.f;
    }
    wsum += wreg;
    const int cnt = min(64, end - base);
#pragma unroll 4
    for (int t = 0; t < cnt; t++) {
      int   s   = __shfl(sreg, t, 64);
      float wgt = __shfl(wreg, t, 64);
      U32H2 cv; cv.u = *(const unsigned*)(h1u + (size_t)s * C_HID + 2 * lane);
      acc.x = fmaf(wgt, (float)cv.h[0], acc.x);
      acc.y = fmaf(wgt, (float)cv.h[1], acc.y);
    }
  }
  float dsum = wsum;
#pragma unroll
  for (int m = 32; m >= 1; m >>= 1) dsum += __shfl_xor(dsum, m, 64);
  const float inv = 1.f / dsum;                    // > 0 via self-loop

  float2 b = *(const float2*)(bias1 + 2 * lane);
  float u0 = fmaxf(acc.x * inv + b.x, 0.f);
  float u1 = fmaxf(acc.y * inv + b.y, 0.f);
  float p[6];
  const float* w2a = W2 + (size_t)(2 * lane) * 6;
#pragma unroll
  for (int o = 0; o < 6; o++) p[o] = u0 * w2a[o] + u1 * w2a[6 + o];
#pragma unroll
  for (int o = 0; o < 6; o++)
#pragma unroll
    for (int msk = 32; msk >= 1; msk >>= 1) p[o] += __shfl_xor(p[o], msk, 64);

  if (lane == 0) {
#pragma unroll
    for (int o = 0; o < 6; o++) h2[(size_t)n * 8 + o] = p[o];
#pragma unroll
    for (int h = 0; h < 3; h++) {
      as2[n * 4 + h] = p[2 * h] * as2w[2 * h] + p[2 * h + 1] * as2w[2 * h + 1];
      ad2[n * 4 + h] = p[2 * h] * ad2w[2 * h] + p[2 * h + 1] * ad2w[2 * h + 1];
    }
  }
}

// ---------------------------------------------------------------------------
// agg2: wave per node, lanes strided over edges, single pass, 9 reductions.
// ---------------------------------------------------------------------------
__global__ __launch_bounds__(256) void agg2_kernel(const float* __restrict__ h2,
    const float* __restrict__ as2, const float* __restrict__ ad2,
    const int* __restrict__ rowptr, const int2* __restrict__ esw,
    const float* __restrict__ bias2, float* __restrict__ out) {
  const int wv = threadIdx.x >> 6, lane = threadIdx.x & 63;
  const int n = blockIdx.x * 4 + wv;
  if (n >= N_NODES) return;
  const int start = rowptr[n], end = rowptr[n + 1];
  const float4 adv = *(const float4*)(ad2 + (size_t)n * 4);

  float d0 = 0.f, d1 = 0.f, d2 = 0.f;
  float a0 = 0.f, a1 = 0.f, a2 = 0.f, a3 = 0.f, a4 = 0.f, a5 = 0.f;
  for (int j = start + lane; j < end; j += 64) {
    int s = esw[j].x;
    float4 asv = *(const float4*)(as2 + (size_t)s * 4);
    float4 hlo = *(const float4*)(h2 + (size_t)s * 8);
    float2 hhi = *(const float2*)(h2 + (size_t)s * 8 + 4);
    float e0 = __expf(leaky(asv.x + adv.x));
    float e1 = __expf(leaky(asv.y + adv.y));
    float e2 = __expf(leaky(asv.z + adv.z));
    d0 += e0; d1 += e1; d2 += e2;
    a0 += e0 * hlo.x; a1 += e0 * hlo.y;
    a2 += e1 * hlo.z; a3 += e1 * hlo.w;
    a4 += e2 * hhi.x; a5 += e2 * hhi.y;
  }
#pragma unroll
  for (int m = 32; m >= 1; m >>= 1) {
    d0 += __shfl_xor(d0, m, 64); d1 += __shfl_xor(d1, m, 64); d2 += __shfl_xor(d2, m, 64);
    a0 += __shfl_xor(a0, m, 64); a1 += __shfl_xor(a1, m, 64); a2 += __shfl_xor(a2, m, 64);
    a3 += __shfl_xor(a3, m, 64); a4 += __shfl_xor(a4, m, 64); a5 += __shfl_xor(a5, m, 64);
  }
  if (lane == 0) {
    float o0 = (a0 / d0 + a2 / d1 + a4 / d2) * (1.f / 3.f) + bias2[0];
    float o1 = (a1 / d0 + a3 / d1 + a5 / d2) * (1.f / 3.f) + bias2[1];
    *(float2*)(out + (size_t)n * 2) = make_float2(o0, o1);
  }
}

// ---------------------------------------------------------------------------
extern "C" void kernel_launch(void* const* d_in, const int* in_sizes, int n_in,
                              void* d_out, int out_size, void* d_ws, size_t ws_size,
                              hipStream_t stream) {
  const float* x        = (const float*)d_in[0];
  const int*   ei       = (const int*)d_in[1];
  const float* W1       = (const float*)d_in[2];
  const float* att_src1 = (const float*)d_in[3];
  const float* att_dst1 = (const float*)d_in[4];
  const float* bias1    = (const float*)d_in[5];
  const float* W2       = (const float*)d_in[6];
  const float* att_src2 = (const float*)d_in[7];
  const float* att_dst2 = (const float*)d_in[8];
  const float* bias2    = (const float*)d_in[9];
  float* out = (float*)d_out;

  char* w = (char*)d_ws;
  auto alloc = [&](size_t bytes) {
    char* p = w;
    w += (bytes + 255) & ~(size_t)255;
    return p;
  };
  unsigned short* h1u    = (unsigned short*)alloc((size_t)N_NODES * C_HID * 2);  // 12.8 MB
  unsigned short* W1Th   = (unsigned short*)alloc((size_t)C_IN * C_HID * 2);
  unsigned short* W1Tl   = (unsigned short*)alloc((size_t)C_IN * C_HID * 2);
  float*          v1s    = (float*)alloc((size_t)C_IN * 4);
  float*          v1d    = (float*)alloc((size_t)C_IN * 4);
  float*          a_src1 = (float*)alloc((size_t)N_NODES * 4);
  float*          a_dst1 = (float*)alloc((size_t)N_NODES * 4);
  int*            deg    = (int*)alloc((size_t)N_NODES * 4);
  int*            rowptr = (int*)alloc((size_t)(N_NODES + 4) * 4);
  int*            cursor = (int*)alloc((size_t)N_NODES * 4);
  int2*           esw    = (int2*)alloc((size_t)E_TOT * 8);                      // 6.8 MB
  float*          h2     = (float*)alloc((size_t)N_NODES * 8 * 4);
  float*          as2    = (float*)alloc((size_t)N_NODES * 4 * 4);
  float*          ad2    = (float*)alloc((size_t)N_NODES * 4 * 4);

  (void)hipMemsetAsync(deg, 0, (size_t)N_NODES * 4, stream);

  prep_v_kernel<<<C_IN / 4, 256, 0, stream>>>(W1, att_src1, att_dst1, v1s, v1d);
  prep_w_kernel<<<16, 256, 0, stream>>>(W1, W1Th, W1Tl);
  deg_kernel<<<(N_EDGES + 255) / 256, 256, 0, stream>>>(ei, deg);
  scan_kernel<<<1, 1024, 0, stream>>>(deg, rowptr, cursor);
  lin1_kernel<<<(N_NODES + 127) / 128, 256, 0, stream>>>(x, W1Th, W1Tl, v1s, v1d,
                                                         h1u, a_src1, a_dst1);
  bucket_kernel<<<(E_TOT + 255) / 256, 256, 0, stream>>>(ei, cursor, a_src1, a_dst1, esw);
  agg1_kernel<<<(N_NODES + 3) / 4, 256, 0, stream>>>(h1u, esw, rowptr, bias1, W2,
                                                     att_src2, att_dst2, h2, as2, ad2);
  agg2_kernel<<<(N_NODES + 3) / 4, 256, 0, stream>>>(h2, as2, ad2, rowptr, esw, bias2, out);
}

// Round 5
// 363.067 us; speedup vs baseline: 1.5007x; 1.0291x over previous
//
#include <hip/hip_runtime.h>

#define N_NODES 50000
#define N_EDGES 800000
#define E_TOT   850000   /* N_EDGES + N_NODES self-loops */
#define C_IN    512
#define C_HID   128
#define NEG     0.2f

typedef _Float16 f16x8 __attribute__((ext_vector_type(8)));
typedef __attribute__((ext_vector_type(4))) float f32x4;

__device__ __forceinline__ float leaky(float x) { return x > 0.f ? x : NEG * x; }

union U32H2 { unsigned u; _Float16 h[2]; float f; };

__device__ __forceinline__ unsigned short f2h(float f) {
  U32H2 c; c.h[0] = (_Float16)f; return (unsigned short)(c.u & 0xffff);
}

// pack two fp32 -> fp16x2 (RTZ hardware op) as raw u32
__device__ __forceinline__ unsigned pk2h(float a, float b) {
  union { __fp16 v __attribute__((ext_vector_type(2))); unsigned u; } c;
  c.v = __builtin_amdgcn_cvt_pkrtz(a, b);
  return c.u;
}

// ---------------------------------------------------------------------------
// prep_v: v1s[k] = sum_c W1[k,c]*att_src1[c], v1d likewise. Wave per k row.
// ---------------------------------------------------------------------------
__global__ __launch_bounds__(256) void prep_v_kernel(const float* __restrict__ W1,
    const float* __restrict__ as1, const float* __restrict__ ad1,
    float* __restrict__ v1s, float* __restrict__ v1d) {
  const int wv = threadIdx.x >> 6, lane = threadIdx.x & 63;
  const int k = blockIdx.x * 4 + wv;
  if (k >= C_IN) return;
  float2 w = *(const float2*)(W1 + (size_t)k * C_HID + 2 * lane);
  float2 a = *(const float2*)(as1 + 2 * lane);
  float2 d = *(const float2*)(ad1 + 2 * lane);
  float s = w.x * a.x + w.y * a.y;
  float t = w.x * d.x + w.y * d.y;
#pragma unroll
  for (int m = 32; m >= 1; m >>= 1) {
    s += __shfl_xor(s, m, 64);
    t += __shfl_xor(t, m, 64);
  }
  if (lane == 0) { v1s[k] = s; v1d[k] = t; }
}

// ---------------------------------------------------------------------------
// prep_w: W1 [512][128] fp32 -> transposed fp16 hi/lo  Wh/Wl [128][512]
// ---------------------------------------------------------------------------
__global__ __launch_bounds__(256) void prep_w_kernel(const float* __restrict__ W1,
    unsigned short* __restrict__ Wh, unsigned short* __restrict__ Wl) {
  int t = blockIdx.x * 256 + threadIdx.x;          // 4096 threads
  int c = t >> 5, k0 = (t & 31) * 16;
  if (c >= C_HID) return;
#pragma unroll
  for (int i = 0; i < 16; i++) {
    float w = W1[(size_t)(k0 + i) * C_HID + c];
    _Float16 hi = (_Float16)w;                     // RNE
    _Float16 lo = (_Float16)(w - (float)hi);
    U32H2 ch; ch.h[0] = hi;
    U32H2 cl; cl.h[0] = lo;
    Wh[(size_t)c * C_IN + k0 + i] = (unsigned short)(ch.u & 0xffff);
    Wl[(size_t)c * C_IN + k0 + i] = (unsigned short)(cl.u & 0xffff);
  }
}

// ---------------------------------------------------------------------------
// lin1: h1 = x @ W1 via fp16 MFMA (x_h*W_hi + x_h*W_lo), fused fp32 a_src/a_dst
// block tile 64x128 (782 blocks = 3.05/CU), BK=32, 256 threads = 4 waves.
// wave owns 16 rows x 128 cols. h1 stored fp16.
// ---------------------------------------------------------------------------
__global__ __launch_bounds__(256) void lin1_kernel(const float* __restrict__ x,
    const unsigned short* __restrict__ Wh, const unsigned short* __restrict__ Wl,
    const float* __restrict__ v1s, const float* __restrict__ v1d,
    unsigned short* __restrict__ h1u, float* __restrict__ a_src, float* __restrict__ a_dst) {
  __shared__ __attribute__((aligned(16))) unsigned short As[64][40];
  __shared__ __attribute__((aligned(16))) unsigned short Bh[128][40];
  __shared__ __attribute__((aligned(16))) unsigned short Bl[128][40];

  const int tid  = threadIdx.x;
  const int lane = tid & 63, wv = tid >> 6;
  const int m0   = blockIdx.x * 64;

  const int arow = tid >> 2, kseg = (tid & 3) * 8;  // A staging: row x 8-float seg
  int grow = m0 + arow;
  if (grow >= N_NODES) grow = N_NODES - 1;          // clamp; stores guarded
  const float* xrow = x + (size_t)grow * C_IN + kseg;

  const int bcol = tid >> 1, bhalf = tid & 1;       // B staging
  const unsigned short* whp = Wh + (size_t)bcol * C_IN + bhalf * 16;
  const unsigned short* wlp = Wl + (size_t)bcol * C_IN + bhalf * 16;

  f32x4 acc[8];
#pragma unroll
  for (int b = 0; b < 8; b++) acc[b] = (f32x4)0.f;
  float ps = 0.f, pd = 0.f;

  const int q = lane >> 4, l15 = lane & 15;

  for (int k0 = 0; k0 < C_IN; k0 += 32) {
    float4 xa = *(const float4*)(xrow + k0);
    float4 xb = *(const float4*)(xrow + k0 + 4);
    float4 vsa = *(const float4*)(v1s + k0 + kseg);
    float4 vsb = *(const float4*)(v1s + k0 + kseg + 4);
    float4 vda = *(const float4*)(v1d + k0 + kseg);
    float4 vdb = *(const float4*)(v1d + k0 + kseg + 4);
    ps += xa.x * vsa.x + xa.y * vsa.y + xa.z * vsa.z + xa.w * vsa.w
        + xb.x * vsb.x + xb.y * vsb.y + xb.z * vsb.z + xb.w * vsb.w;
    pd += xa.x * vda.x + xa.y * vda.y + xa.z * vda.z + xa.w * vda.w
        + xb.x * vdb.x + xb.y * vdb.y + xb.z * vdb.z + xb.w * vdb.w;
    *(uint4*)&As[arow][kseg] = make_uint4(pk2h(xa.x, xa.y), pk2h(xa.z, xa.w),
                                          pk2h(xb.x, xb.y), pk2h(xb.z, xb.w));
    {
      const int4* sh = (const int4*)(whp + k0);
      const int4* sl = (const int4*)(wlp + k0);
      int4* dh = (int4*)&Bh[bcol][bhalf * 16];
      int4* dl = (int4*)&Bl[bcol][bhalf * 16];
      dh[0] = sh[0]; dh[1] = sh[1];
      dl[0] = sl[0]; dl[1] = sl[1];
    }
    __syncthreads();

    f16x8 a0 = *(const f16x8*)&As[wv * 16 + l15][q * 8];
#pragma unroll
    for (int t = 0; t < 8; t++) {
      f16x8 bh = *(const f16x8*)&Bh[t * 16 + l15][q * 8];
      f16x8 bl = *(const f16x8*)&Bl[t * 16 + l15][q * 8];
      acc[t] = __builtin_amdgcn_mfma_f32_16x16x32_f16(a0, bh, acc[t], 0, 0, 0);
      acc[t] = __builtin_amdgcn_mfma_f32_16x16x32_f16(a0, bl, acc[t], 0, 0, 0);
    }
    __syncthreads();
  }

  // attention dots: reduce over the 4 staging threads sharing a row
  ps += __shfl_xor(ps, 1, 64); ps += __shfl_xor(ps, 2, 64);
  pd += __shfl_xor(pd, 1, 64); pd += __shfl_xor(pd, 2, 64);
  if ((tid & 3) == 0) {
    int row = m0 + arow;
    if (row < N_NODES) { a_src[row] = ps; a_dst[row] = pd; }
  }

  // C store (fp16): C/D layout col=lane&15, row=(lane>>4)*4+reg
  {
    int rbase = m0 + wv * 16 + q * 4;
#pragma unroll
    for (int t = 0; t < 8; t++) {
#pragma unroll
      for (int ri = 0; ri < 4; ri++) {
        int row = rbase + ri;
        if (row < N_NODES)
          h1u[(size_t)row * C_HID + t * 16 + l15] = f2h(acc[t][ri]);
      }
    }
  }
}

// ---------------------------------------------------------------------------
// CSR build
// ---------------------------------------------------------------------------
__global__ void deg_kernel(const int* __restrict__ ei, int* __restrict__ deg) {
  int e = blockIdx.x * blockDim.x + threadIdx.x;
  if (e >= N_EDGES) return;
  atomicAdd(&deg[ei[N_EDGES + e]], 1);
}

__global__ __launch_bounds__(1024) void scan_kernel(const int* __restrict__ deg,
                                                    int* __restrict__ rowptr,
                                                    int* __restrict__ cursor) {
  __shared__ int wsum[16];
  const int tid = threadIdx.x, lane = tid & 63, wv = tid >> 6;
  int carry = 0;
  for (int base = 0; base < N_NODES; base += 8192) {   // 7 chunks
    int i0 = base + tid * 8;
    int v[8];
    if (i0 + 8 <= N_NODES) {
      int4 va = *(const int4*)(deg + i0);
      int4 vb = *(const int4*)(deg + i0 + 4);
      v[0]=va.x+1; v[1]=va.y+1; v[2]=va.z+1; v[3]=va.w+1;
      v[4]=vb.x+1; v[5]=vb.y+1; v[6]=vb.z+1; v[7]=vb.w+1;
    } else {
#pragma unroll
      for (int i = 0; i < 8; i++) v[i] = (i0 + i < N_NODES) ? deg[i0 + i] + 1 : 0;
    }
    int tsum = 0;
#pragma unroll
    for (int i = 0; i < 8; i++) tsum += v[i];
    int sc = tsum;
#pragma unroll
    for (int off = 1; off < 64; off <<= 1) {
      int t = __shfl_up(sc, off, 64);
      if (lane >= off) sc += t;
    }
    if (lane == 63) wsum[wv] = sc;
    __syncthreads();
    if (wv == 0 && lane < 16) {
      int s = wsum[lane];
#pragma unroll
      for (int off = 1; off < 16; off <<= 1) {
        int t = __shfl_up(s, off, 64);
        if (lane >= off) s += t;
      }
      wsum[lane] = s;
    }
    __syncthreads();
    int ex = carry + (wv ? wsum[wv - 1] : 0) + sc - tsum;
#pragma unroll
    for (int i = 0; i < 8; i++) {
      if (i0 + i < N_NODES) { rowptr[i0 + i] = ex; cursor[i0 + i] = ex; }
      ex += v[i];
    }
    carry += wsum[15];
    __syncthreads();
  }
  if (tid == 0) rowptr[N_NODES] = carry;
}

__global__ void bucket_kernel(const int* __restrict__ ei, int* __restrict__ cursor,
                              const float* __restrict__ a_src, const float* __restrict__ a_dst,
                              int2* __restrict__ esw) {
  int e = blockIdx.x * blockDim.x + threadIdx.x;
  if (e >= E_TOT) return;
  int src, dst;
  if (e < N_EDGES) { src = ei[e]; dst = ei[N_EDGES + e]; }
  else             { src = dst = e - N_EDGES; }
  float w = __expf(leaky(a_src[src] + a_dst[dst]));
  int slot = atomicAdd(&cursor[dst], 1);
  U32H2 c; c.f = w;
  esw[slot] = make_int2(src, (int)c.u);
}

// ---------------------------------------------------------------------------
// agg1: wave per node, quarter-wave edge parallelism. lane = (q in [0,4), r in
// [0,16)); lane gathers 16 B (channels 8r..8r+7) of edge 8i+q and 8i+4+q -> 8
// independent gather chains per wave. Channel fold via shfl_xor(16/32).
// Epilogue (8-ch-per-lane form) fuses +bias1, ReLU, W2 (128->6), att2 dots.
// ---------------------------------------------------------------------------
__global__ __launch_bounds__(256) void agg1_kernel(const unsigned short* __restrict__ h1u,
    const int2* __restrict__ esw, const int* __restrict__ rowptr,
    const float* __restrict__ bias1, const float* __restrict__ W2,
    const float* __restrict__ as2w, const float* __restrict__ ad2w,
    float* __restrict__ h2, float* __restrict__ as2, float* __restrict__ ad2) {
  const int wv = threadIdx.x >> 6, lane = threadIdx.x & 63;
  const int q = lane >> 4, r = lane & 15;
  const int n = blockIdx.x * 4 + wv;
  if (n >= N_NODES) return;
  const int start = rowptr[n], end = rowptr[n + 1];

  float acc[8];
#pragma unroll
  for (int i = 0; i < 8; i++) acc[i] = 0.f;
  float wsum = 0.f;

  const unsigned short* hbase = h1u + r * 8;

  for (int base = start; base < end; base += 64) {
    int idx = base + lane;
    int sreg = 0; float wreg = 0.f;
    if (idx < end) {
      int2 sv = esw[idx];
      sreg = sv.x;
      U32H2 c; c.u = (unsigned)sv.y;
      wreg = c.f;
    }
    wsum += wreg;
    const int cnt = min(64, end - base);
    const int nit = (cnt + 7) >> 3;
    for (int i = 0; i < nit; i++) {
      int e0 = 8 * i + q, e1 = 8 * i + 4 + q;
      int   s0 = __shfl(sreg, e0, 64);
      int   s1 = __shfl(sreg, e1, 64);
      float w0 = __shfl(wreg, e0, 64);
      float w1 = __shfl(wreg, e1, 64);
      uint4 g0 = *(const uint4*)(hbase + (size_t)s0 * C_HID);
      uint4 g1 = *(const uint4*)(hbase + (size_t)s1 * C_HID);
      U32H2 c0, c1, c2, c3;
      c0.u = g0.x; c1.u = g0.y; c2.u = g0.z; c3.u = g0.w;
      acc[0] = fmaf(w0, (float)c0.h[0], acc[0]); acc[1] = fmaf(w0, (float)c0.h[1], acc[1]);
      acc[2] = fmaf(w0, (float)c1.h[0], acc[2]); acc[3] = fmaf(w0, (float)c1.h[1], acc[3]);
      acc[4] = fmaf(w0, (float)c2.h[0], acc[4]); acc[5] = fmaf(w0, (float)c2.h[1], acc[5]);
      acc[6] = fmaf(w0, (float)c3.h[0], acc[6]); acc[7] = fmaf(w0, (float)c3.h[1], acc[7]);
      c0.u = g1.x; c1.u = g1.y; c2.u = g1.z; c3.u = g1.w;
      acc[0] = fmaf(w1, (float)c0.h[0], acc[0]); acc[1] = fmaf(w1, (float)c0.h[1], acc[1]);
      acc[2] = fmaf(w1, (float)c1.h[0], acc[2]); acc[3] = fmaf(w1, (float)c1.h[1], acc[3]);
      acc[4] = fmaf(w1, (float)c2.h[0], acc[4]); acc[5] = fmaf(w1, (float)c2.h[1], acc[5]);
      acc[6] = fmaf(w1, (float)c3.h[0], acc[6]); acc[7] = fmaf(w1, (float)c3.h[1], acc[7]);
    }
  }

  // fold quarters: every lane gets full channel sums for channels 8r..8r+7
#pragma unroll
  for (int i = 0; i < 8; i++) {
    acc[i] += __shfl_xor(acc[i], 16, 64);
    acc[i] += __shfl_xor(acc[i], 32, 64);
  }
  // dsum over all 64 slots
#pragma unroll
  for (int m = 32; m >= 1; m >>= 1) wsum += __shfl_xor(wsum, m, 64);
  const float inv = 1.f / wsum;                    // > 0 via self-loop

  // epilogue: u_c = relu(acc_c*inv + bias1_c) for c = 8r..8r+7
  float4 ba = *(const float4*)(bias1 + r * 8);
  float4 bb = *(const float4*)(bias1 + r * 8 + 4);
  float u[8] = {fmaxf(acc[0] * inv + ba.x, 0.f), fmaxf(acc[1] * inv + ba.y, 0.f),
                fmaxf(acc[2] * inv + ba.z, 0.f), fmaxf(acc[3] * inv + ba.w, 0.f),
                fmaxf(acc[4] * inv + bb.x, 0.f), fmaxf(acc[5] * inv + bb.y, 0.f),
                fmaxf(acc[6] * inv + bb.z, 0.f), fmaxf(acc[7] * inv + bb.w, 0.f)};
  float p[6] = {0, 0, 0, 0, 0, 0};
#pragma unroll
  for (int i = 0; i < 8; i++) {
    const float* w2r = W2 + (size_t)(r * 8 + i) * 6;
#pragma unroll
    for (int o = 0; o < 6; o++) p[o] = fmaf(u[i], w2r[o], p[o]);
  }
#pragma unroll
  for (int o = 0; o < 6; o++) {
#pragma unroll
    for (int msk = 8; msk >= 1; msk >>= 1) p[o] += __shfl_xor(p[o], msk, 64);
  }

  if (lane == 0) {
#pragma unroll
    for (int o = 0; o < 6; o++) h2[(size_t)n * 8 + o] = p[o];
#pragma unroll
    for (int h = 0; h < 3; h++) {
      as2[n * 4 + h] = p[2 * h] * as2w[2 * h] + p[2 * h + 1] * as2w[2 * h + 1];
      ad2[n * 4 + h] = p[2 * h] * ad2w[2 * h] + p[2 * h + 1] * ad2w[2 * h + 1];
    }
  }
}

// ---------------------------------------------------------------------------
// agg2: 16 lanes per node (4 nodes/wave), lanes strided over edges,
// single pass, 4-step reductions. out = mean over heads + bias2.
// ---------------------------------------------------------------------------
__global__ __launch_bounds__(256) void agg2_kernel(const float* __restrict__ h2,
    const float* __restrict__ as2, const float* __restrict__ ad2,
    const int* __restrict__ rowptr, const int2* __restrict__ esw,
    const float* __restrict__ bias2, float* __restrict__ out) {
  const int wv = threadIdx.x >> 6, lane = threadIdx.x & 63;
  const int q = lane >> 4, r = lane & 15;
  const int n = blockIdx.x * 16 + wv * 4 + q;
  if (n >= N_NODES) return;
  const int start = rowptr[n], end = rowptr[n + 1];
  const float4 adv = *(const float4*)(ad2 + (size_t)n * 4);

  float d0 = 0.f, d1 = 0.f, d2 = 0.f;
  float a0 = 0.f, a1 = 0.f, a2 = 0.f, a3 = 0.f, a4 = 0.f, a5 = 0.f;
  for (int j = start + r; j < end; j += 16) {
    int s = esw[j].x;
    float4 asv = *(const float4*)(as2 + (size_t)s * 4);
    float4 hlo = *(const float4*)(h2 + (size_t)s * 8);
    float2 hhi = *(const float2*)(h2 + (size_t)s * 8 + 4);
    float e0 = __expf(leaky(asv.x + adv.x));
    float e1 = __expf(leaky(asv.y + adv.y));
    float e2 = __expf(leaky(asv.z + adv.z));
    d0 += e0; d1 += e1; d2 += e2;
    a0 += e0 * hlo.x; a1 += e0 * hlo.y;
    a2 += e1 * hlo.z; a3 += e1 * hlo.w;
    a4 += e2 * hhi.x; a5 += e2 * hhi.y;
  }
#pragma unroll
  for (int m = 8; m >= 1; m >>= 1) {
    d0 += __shfl_xor(d0, m, 64); d1 += __shfl_xor(d1, m, 64); d2 += __shfl_xor(d2, m, 64);
    a0 += __shfl_xor(a0, m, 64); a1 += __shfl_xor(a1, m, 64); a2 += __shfl_xor(a2, m, 64);
    a3 += __shfl_xor(a3, m, 64); a4 += __shfl_xor(a4, m, 64); a5 += __shfl_xor(a5, m, 64);
  }
  if (r == 0) {
    float o0 = (a0 / d0 + a2 / d1 + a4 / d2) * (1.f / 3.f) + bias2[0];
    float o1 = (a1 / d0 + a3 / d1 + a5 / d2) * (1.f / 3.f) + bias2[1];
    *(float2*)(out + (size_t)n * 2) = make_float2(o0, o1);
  }
}

// ---------------------------------------------------------------------------
extern "C" void kernel_launch(void* const* d_in, const int* in_sizes, int n_in,
                              void* d_out, int out_size, void* d_ws, size_t ws_size,
                              hipStream_t stream) {
  const float* x        = (const float*)d_in[0];
  const int*   ei       = (const int*)d_in[1];
  const float* W1       = (const float*)d_in[2];
  const float* att_src1 = (const float*)d_in[3];
  const float* att_dst1 = (const float*)d_in[4];
  const float* bias1    = (const float*)d_in[5];
  const float* W2       = (const float*)d_in[6];
  const float* att_src2 = (const float*)d_in[7];
  const float* att_dst2 = (const float*)d_in[8];
  const float* bias2    = (const float*)d_in[9];
  float* out = (float*)d_out;

  char* w = (char*)d_ws;
  auto alloc = [&](size_t bytes) {
    char* p = w;
    w += (bytes + 255) & ~(size_t)255;
    return p;
  };
  unsigned short* h1u    = (unsigned short*)alloc((size_t)N_NODES * C_HID * 2);  // 12.8 MB
  unsigned short* W1Th   = (unsigned short*)alloc((size_t)C_IN * C_HID * 2);
  unsigned short* W1Tl   = (unsigned short*)alloc((size_t)C_IN * C_HID * 2);
  float*          v1s    = (float*)alloc((size_t)C_IN * 4);
  float*          v1d    = (float*)alloc((size_t)C_IN * 4);
  float*          a_src1 = (float*)alloc((size_t)N_NODES * 4);
  float*          a_dst1 = (float*)alloc((size_t)N_NODES * 4);
  int*            deg    = (int*)alloc((size_t)N_NODES * 4);
  int*            rowptr = (int*)alloc((size_t)(N_NODES + 4) * 4);
  int*            cursor = (int*)alloc((size_t)N_NODES * 4);
  int2*           esw    = (int2*)alloc((size_t)E_TOT * 8);                      // 6.8 MB
  float*          h2     = (float*)alloc((size_t)N_NODES * 8 * 4);
  float*          as2    = (float*)alloc((size_t)N_NODES * 4 * 4);
  float*          ad2    = (float*)alloc((size_t)N_NODES * 4 * 4);

  (void)hipMemsetAsync(deg, 0, (size_t)N_NODES * 4, stream);

  prep_v_kernel<<<C_IN / 4, 256, 0, stream>>>(W1, att_src1, att_dst1, v1s, v1d);
  prep_w_kernel<<<16, 256, 0, stream>>>(W1, W1Th, W1Tl);
  deg_kernel<<<(N_EDGES + 255) / 256, 256, 0, stream>>>(ei, deg);
  scan_kernel<<<1, 1024, 0, stream>>>(deg, rowptr, cursor);
  lin1_kernel<<<(N_NODES + 63) / 64, 256, 0, stream>>>(x, W1Th, W1Tl, v1s, v1d,
                                                       h1u, a_src1, a_dst1);
  bucket_kernel<<<(E_TOT + 255) / 256, 256, 0, stream>>>(ei, cursor, a_src1, a_dst1, esw);
  agg1_kernel<<<(N_NODES + 3) / 4, 256, 0, stream>>>(h1u, esw, rowptr, bias1, W2,
                                                     att_src2, att_dst2, h2, as2, ad2);
  agg2_kernel<<<(N_NODES + 15) / 16, 256, 0, stream>>>(h2, as2, ad2, rowptr, esw, bias2, out);
}

// Round 6
// 354.110 us; speedup vs baseline: 1.5387x; 1.0253x over previous
//
#include <hip/hip_runtime.h>

#define N_NODES 50000
#define N_EDGES 800000
#define E_TOT   850000   /* N_EDGES + N_NODES self-loops */
#define C_IN    512
#define C_HID   128
#define NEG     0.2f

typedef _Float16 f16x8 __attribute__((ext_vector_type(8)));
typedef __attribute__((ext_vector_type(4))) float f32x4;

__device__ __forceinline__ float leaky(float x) { return x > 0.f ? x : NEG * x; }

union U32H2 { unsigned u; _Float16 h[2]; float f; };
union BFrag { uint4 u; f16x8 h; };

__device__ __forceinline__ unsigned short f2h(float f) {
  U32H2 c; c.h[0] = (_Float16)f; return (unsigned short)(c.u & 0xffff);
}

// pack two fp32 -> fp16x2 (RTZ hardware op) as raw u32
__device__ __forceinline__ unsigned pk2h(float a, float b) {
  union { __fp16 v __attribute__((ext_vector_type(2))); unsigned u; } c;
  c.v = __builtin_amdgcn_cvt_pkrtz(a, b);
  return c.u;
}

// ---------------------------------------------------------------------------
// prep_v: v1s[k] = sum_c W1[k,c]*att_src1[c], v1d likewise. Wave per k row.
// ---------------------------------------------------------------------------
__global__ __launch_bounds__(256) void prep_v_kernel(const float* __restrict__ W1,
    const float* __restrict__ as1, const float* __restrict__ ad1,
    float* __restrict__ v1s, float* __restrict__ v1d) {
  const int wv = threadIdx.x >> 6, lane = threadIdx.x & 63;
  const int k = blockIdx.x * 4 + wv;
  if (k >= C_IN) return;
  float2 w = *(const float2*)(W1 + (size_t)k * C_HID + 2 * lane);
  float2 a = *(const float2*)(as1 + 2 * lane);
  float2 d = *(const float2*)(ad1 + 2 * lane);
  float s = w.x * a.x + w.y * a.y;
  float t = w.x * d.x + w.y * d.y;
#pragma unroll
  for (int m = 32; m >= 1; m >>= 1) {
    s += __shfl_xor(s, m, 64);
    t += __shfl_xor(t, m, 64);
  }
  if (lane == 0) { v1s[k] = s; v1d[k] = t; }
}

// ---------------------------------------------------------------------------
// prep_w: W1 [512][128] fp32 -> MFMA-fragment-order fp16 hi/lo swizzle.
// Chunk (kblk in [0,16), ct in [0,8), h in {hi,lo}) = 512 ushorts, lane-linear:
// lane (q*16+l15) holds 16 B = W[k0+q*8 .. +8][ct*16+l15], so lin1's B load is
// one fully-coalesced dwordx4 per fragment. thread = (c, kc) covering k=kc*8..+8.
// ---------------------------------------------------------------------------
__global__ __launch_bounds__(256) void prep_w_kernel(const float* __restrict__ W1,
    unsigned short* __restrict__ Wswz) {
  int t = blockIdx.x * 256 + threadIdx.x;          // 8192 threads
  int c = t >> 6, kc = t & 63;                     // c in [0,128), k = kc*8
  if (c >= C_HID) return;
  int kblk = kc >> 2, q = kc & 3;
  int ct = c >> 4, l15 = c & 15;
  int lane = q * 16 + l15;
  unsigned short hb[8], lb[8];
#pragma unroll
  for (int i = 0; i < 8; i++) {
    float w = W1[(size_t)(kc * 8 + i) * C_HID + c];
    _Float16 hi = (_Float16)w;                     // RNE
    _Float16 lo = (_Float16)(w - (float)hi);
    U32H2 ch; ch.h[0] = hi;
    U32H2 cl; cl.h[0] = lo;
    hb[i] = (unsigned short)(ch.u & 0xffff);
    lb[i] = (unsigned short)(cl.u & 0xffff);
  }
  size_t chunk0 = ((size_t)(kblk * 8 + ct) * 2) * 512;   // ushort units
  *(uint4*)&Wswz[chunk0 + (size_t)lane * 8]       = *(uint4*)hb;
  *(uint4*)&Wswz[chunk0 + 512 + (size_t)lane * 8] = *(uint4*)lb;
}

// ---------------------------------------------------------------------------
// lin1: h1 = x @ W1 via fp16 MFMA (x_h*W_hi + x_h*W_lo), fused fp32 a_src/a_dst.
// Block 64x128, 4 waves; wave owns ALL 64 rows x 32 cols (ct = 2wv, 2wv+1).
// A staged in LDS (5 KB, transpose+cvt); B direct global->register from Wswz
// (L2-resident, coalesced). 16 MFMA per wave per k0 vs 4 ds_read_b128.
// ---------------------------------------------------------------------------
__global__ __launch_bounds__(256) void lin1_kernel(const float* __restrict__ x,
    const unsigned short* __restrict__ Wswz,
    const float* __restrict__ v1s, const float* __restrict__ v1d,
    unsigned short* __restrict__ h1u, float* __restrict__ a_src, float* __restrict__ a_dst) {
  __shared__ __attribute__((aligned(16))) unsigned short As[64][40];  // stride 80 B = 16B-aligned

  const int tid  = threadIdx.x;
  const int lane = tid & 63, wv = tid >> 6;
  const int m0   = blockIdx.x * 64;

  const int arow = tid >> 2, kseg = (tid & 3) * 8;  // A staging: row x 8-float seg
  int grow = m0 + arow;
  if (grow >= N_NODES) grow = N_NODES - 1;          // clamp; stores guarded
  const float* xrow = x + (size_t)grow * C_IN + kseg;

  f32x4 acc[4][2];
#pragma unroll
  for (int rt = 0; rt < 4; rt++) { acc[rt][0] = (f32x4)0.f; acc[rt][1] = (f32x4)0.f; }
  float ps = 0.f, pd = 0.f;

  const int q = lane >> 4, l15 = lane & 15;

  float4 xa = *(const float4*)(xrow);
  float4 xb = *(const float4*)(xrow + 4);

  for (int kblk = 0; kblk < 16; kblk++) {
    const int k0 = kblk * 32;
    // fused attention-dot partials on fp32 x
    float4 vsa = *(const float4*)(v1s + k0 + kseg);
    float4 vsb = *(const float4*)(v1s + k0 + kseg + 4);
    float4 vda = *(const float4*)(v1d + k0 + kseg);
    float4 vdb = *(const float4*)(v1d + k0 + kseg + 4);
    ps += xa.x * vsa.x + xa.y * vsa.y + xa.z * vsa.z + xa.w * vsa.w
        + xb.x * vsb.x + xb.y * vsb.y + xb.z * vsb.z + xb.w * vsb.w;
    pd += xa.x * vda.x + xa.y * vda.y + xa.z * vda.z + xa.w * vda.w
        + xb.x * vdb.x + xb.y * vdb.y + xb.z * vdb.z + xb.w * vdb.w;
    uint4 pk = make_uint4(pk2h(xa.x, xa.y), pk2h(xa.z, xa.w),
                          pk2h(xb.x, xb.y), pk2h(xb.z, xb.w));

    __syncthreads();                                // prev iter's As reads done
    *(uint4*)&As[arow][kseg] = pk;
    // prefetch next x chunk (overlaps staging + barrier)
    if (kblk < 15) {
      xa = *(const float4*)(xrow + k0 + 32);
      xb = *(const float4*)(xrow + k0 + 36);
    }
    __syncthreads();                                // As ready

    // B fragments: global->register, L2-resident, coalesced
    const unsigned short* bp = Wswz + ((size_t)(kblk * 8 + wv * 2) * 2) * 512 + (size_t)lane * 8;
    BFrag b00, b01, b10, b11;
    b00.u = *(const uint4*)(bp);
    b01.u = *(const uint4*)(bp + 512);
    b10.u = *(const uint4*)(bp + 1024);
    b11.u = *(const uint4*)(bp + 1536);

#pragma unroll
    for (int rt = 0; rt < 4; rt++) {
      f16x8 af = *(const f16x8*)&As[rt * 16 + l15][q * 8];
      acc[rt][0] = __builtin_amdgcn_mfma_f32_16x16x32_f16(af, b00.h, acc[rt][0], 0, 0, 0);
      acc[rt][0] = __builtin_amdgcn_mfma_f32_16x16x32_f16(af, b01.h, acc[rt][0], 0, 0, 0);
      acc[rt][1] = __builtin_amdgcn_mfma_f32_16x16x32_f16(af, b10.h, acc[rt][1], 0, 0, 0);
      acc[rt][1] = __builtin_amdgcn_mfma_f32_16x16x32_f16(af, b11.h, acc[rt][1], 0, 0, 0);
    }
  }

  // attention dots: reduce over the 4 staging threads sharing a row
  ps += __shfl_xor(ps, 1, 64); ps += __shfl_xor(ps, 2, 64);
  pd += __shfl_xor(pd, 1, 64); pd += __shfl_xor(pd, 2, 64);
  if ((tid & 3) == 0) {
    int row = m0 + arow;
    if (row < N_NODES) { a_src[row] = ps; a_dst[row] = pd; }
  }

  // C store (fp16): C/D layout col=lane&15, row=(lane>>4)*4+reg
#pragma unroll
  for (int rt = 0; rt < 4; rt++) {
    int rbase = m0 + rt * 16 + q * 4;
#pragma unroll
    for (int ct = 0; ct < 2; ct++) {
      int col = wv * 32 + ct * 16 + l15;
#pragma unroll
      for (int ri = 0; ri < 4; ri++) {
        int row = rbase + ri;
        if (row < N_NODES)
          h1u[(size_t)row * C_HID + col] = f2h(acc[rt][ct][ri]);
      }
    }
  }
}

// ---------------------------------------------------------------------------
// CSR build
// ---------------------------------------------------------------------------
__global__ void deg_kernel(const int* __restrict__ ei, int* __restrict__ deg) {
  int e = blockIdx.x * blockDim.x + threadIdx.x;
  if (e >= N_EDGES) return;
  atomicAdd(&deg[ei[N_EDGES + e]], 1);
}

__global__ __launch_bounds__(1024) void scan_kernel(const int* __restrict__ deg,
                                                    int* __restrict__ rowptr,
                                                    int* __restrict__ cursor) {
  __shared__ int wsum[16];
  const int tid = threadIdx.x, lane = tid & 63, wv = tid >> 6;
  int carry = 0;
  for (int base = 0; base < N_NODES; base += 8192) {   // 7 chunks
    int i0 = base + tid * 8;
    int v[8];
    if (i0 + 8 <= N_NODES) {
      int4 va = *(const int4*)(deg + i0);
      int4 vb = *(const int4*)(deg + i0 + 4);
      v[0]=va.x+1; v[1]=va.y+1; v[2]=va.z+1; v[3]=va.w+1;
      v[4]=vb.x+1; v[5]=vb.y+1; v[6]=vb.z+1; v[7]=vb.w+1;
    } else {
#pragma unroll
      for (int i = 0; i < 8; i++) v[i] = (i0 + i < N_NODES) ? deg[i0 + i] + 1 : 0;
    }
    int tsum = 0;
#pragma unroll
    for (int i = 0; i < 8; i++) tsum += v[i];
    int sc = tsum;
#pragma unroll
    for (int off = 1; off < 64; off <<= 1) {
      int t = __shfl_up(sc, off, 64);
      if (lane >= off) sc += t;
    }
    if (lane == 63) wsum[wv] = sc;
    __syncthreads();
    if (wv == 0 && lane < 16) {
      int s = wsum[lane];
#pragma unroll
      for (int off = 1; off < 16; off <<= 1) {
        int t = __shfl_up(s, off, 64);
        if (lane >= off) s += t;
      }
      wsum[lane] = s;
    }
    __syncthreads();
    int ex = carry + (wv ? wsum[wv - 1] : 0) + sc - tsum;
#pragma unroll
    for (int i = 0; i < 8; i++) {
      if (i0 + i < N_NODES) { rowptr[i0 + i] = ex; cursor[i0 + i] = ex; }
      ex += v[i];
    }
    carry += wsum[15];
    __syncthreads();
  }
  if (tid == 0) rowptr[N_NODES] = carry;
}

__global__ void bucket_kernel(const int* __restrict__ ei, int* __restrict__ cursor,
                              const float* __restrict__ a_src, const float* __restrict__ a_dst,
                              int2* __restrict__ esw) {
  int e = blockIdx.x * blockDim.x + threadIdx.x;
  if (e >= E_TOT) return;
  int src, dst;
  if (e < N_EDGES) { src = ei[e]; dst = ei[N_EDGES + e]; }
  else             { src = dst = e - N_EDGES; }
  float w = __expf(leaky(a_src[src] + a_dst[dst]));
  int slot = atomicAdd(&cursor[dst], 1);
  U32H2 c; c.f = w;
  esw[slot] = make_int2(src, (int)c.u);
}

// ---------------------------------------------------------------------------
// agg1: wave per node, quarter-wave edge parallelism. lane = (q in [0,4), r in
// [0,16)); lane gathers 16 B (channels 8r..8r+7) of edge 8i+q and 8i+4+q -> 8
// independent gather chains per wave. Channel fold via shfl_xor(16/32).
// Epilogue (8-ch-per-lane form) fuses +bias1, ReLU, W2 (128->6), att2 dots.
// ---------------------------------------------------------------------------
__global__ __launch_bounds__(256) void agg1_kernel(const unsigned short* __restrict__ h1u,
    const int2* __restrict__ esw, const int* __restrict__ rowptr,
    const float* __restrict__ bias1, const float* __restrict__ W2,
    const float* __restrict__ as2w, const float* __restrict__ ad2w,
    float* __restrict__ h2, float* __restrict__ as2, float* __restrict__ ad2) {
  const int wv = threadIdx.x >> 6, lane = threadIdx.x & 63;
  const int q = lane >> 4, r = lane & 15;
  const int n = blockIdx.x * 4 + wv;
  if (n >= N_NODES) return;
  const int start = rowptr[n], end = rowptr[n + 1];

  float acc[8];
#pragma unroll
  for (int i = 0; i < 8; i++) acc[i] = 0.f;
  float wsum = 0.f;

  const unsigned short* hbase = h1u + r * 8;

  for (int base = start; base < end; base += 64) {
    int idx = base + lane;
    int sreg = 0; float wreg = 0.f;
    if (idx < end) {
      int2 sv = esw[idx];
      sreg = sv.x;
      U32H2 c; c.u = (unsigned)sv.y;
      wreg = c.f;
    }
    wsum += wreg;
    const int cnt = min(64, end - base);
    const int nit = (cnt + 7) >> 3;
    for (int i = 0; i < nit; i++) {
      int e0 = 8 * i + q, e1 = 8 * i + 4 + q;
      int   s0 = __shfl(sreg, e0, 64);
      int   s1 = __shfl(sreg, e1, 64);
      float w0 = __shfl(wreg, e0, 64);
      float w1 = __shfl(wreg, e1, 64);
      uint4 g0 = *(const uint4*)(hbase + (size_t)s0 * C_HID);
      uint4 g1 = *(const uint4*)(hbase + (size_t)s1 * C_HID);
      U32H2 c0, c1, c2, c3;
      c0.u = g0.x; c1.u = g0.y; c2.u = g0.z; c3.u = g0.w;
      acc[0] = fmaf(w0, (float)c0.h[0], acc[0]); acc[1] = fmaf(w0, (float)c0.h[1], acc[1]);
      acc[2] = fmaf(w0, (float)c1.h[0], acc[2]); acc[3] = fmaf(w0, (float)c1.h[1], acc[3]);
      acc[4] = fmaf(w0, (float)c2.h[0], acc[4]); acc[5] = fmaf(w0, (float)c2.h[1], acc[5]);
      acc[6] = fmaf(w0, (float)c3.h[0], acc[6]); acc[7] = fmaf(w0, (float)c3.h[1], acc[7]);
      c0.u = g1.x; c1.u = g1.y; c2.u = g1.z; c3.u = g1.w;
      acc[0] = fmaf(w1, (float)c0.h[0], acc[0]); acc[1] = fmaf(w1, (float)c0.h[1], acc[1]);
      acc[2] = fmaf(w1, (float)c1.h[0], acc[2]); acc[3] = fmaf(w1, (float)c1.h[1], acc[3]);
      acc[4] = fmaf(w1, (float)c2.h[0], acc[4]); acc[5] = fmaf(w1, (float)c2.h[1], acc[5]);
      acc[6] = fmaf(w1, (float)c3.h[0], acc[6]); acc[7] = fmaf(w1, (float)c3.h[1], acc[7]);
    }
  }

  // fold quarters: every lane gets full channel sums for channels 8r..8r+7
#pragma unroll
  for (int i = 0; i < 8; i++) {
    acc[i] += __shfl_xor(acc[i], 16, 64);
    acc[i] += __shfl_xor(acc[i], 32, 64);
  }
  // dsum over all 64 slots
#pragma unroll
  for (int m = 32; m >= 1; m >>= 1) wsum += __shfl_xor(wsum, m, 64);
  const float inv = 1.f / wsum;                    // > 0 via self-loop

  // epilogue: u_c = relu(acc_c*inv + bias1_c) for c = 8r..8r+7
  float4 ba = *(const float4*)(bias1 + r * 8);
  float4 bb = *(const float4*)(bias1 + r * 8 + 4);
  float u[8] = {fmaxf(acc[0] * inv + ba.x, 0.f), fmaxf(acc[1] * inv + ba.y, 0.f),
                fmaxf(acc[2] * inv + ba.z, 0.f), fmaxf(acc[3] * inv + ba.w, 0.f),
                fmaxf(acc[4] * inv + bb.x, 0.f), fmaxf(acc[5] * inv + bb.y, 0.f),
                fmaxf(acc[6] * inv + bb.z, 0.f), fmaxf(acc[7] * inv + bb.w, 0.f)};
  float p[6] = {0, 0, 0, 0, 0, 0};
#pragma unroll
  for (int i = 0; i < 8; i++) {
    const float* w2r = W2 + (size_t)(r * 8 + i) * 6;
#pragma unroll
    for (int o = 0; o < 6; o++) p[o] = fmaf(u[i], w2r[o], p[o]);
  }
#pragma unroll
  for (int o = 0; o < 6; o++) {
#pragma unroll
    for (int msk = 8; msk >= 1; msk >>= 1) p[o] += __shfl_xor(p[o], msk, 64);
  }

  if (lane == 0) {
#pragma unroll
    for (int o = 0; o < 6; o++) h2[(size_t)n * 8 + o] = p[o];
#pragma unroll
    for (int h = 0; h < 3; h++) {
      as2[n * 4 + h] = p[2 * h] * as2w[2 * h] + p[2 * h + 1] * as2w[2 * h + 1];
      ad2[n * 4 + h] = p[2 * h] * ad2w[2 * h] + p[2 * h + 1] * ad2w[2 * h + 1];
    }
  }
}

// ---------------------------------------------------------------------------
// agg2: 16 lanes per node (4 nodes/wave), lanes strided over edges,
// single pass, 4-step reductions. out = mean over heads + bias2.
// ---------------------------------------------------------------------------
__global__ __launch_bounds__(256) void agg2_kernel(const float* __restrict__ h2,
    const float* __restrict__ as2, const float* __restrict__ ad2,
    const int* __restrict__ rowptr, const int2* __restrict__ esw,
    const float* __restrict__ bias2, float* __restrict__ out) {
  const int wv = threadIdx.x >> 6, lane = threadIdx.x & 63;
  const int q = lane >> 4, r = lane & 15;
  const int n = blockIdx.x * 16 + wv * 4 + q;
  if (n >= N_NODES) return;
  const int start = rowptr[n], end = rowptr[n + 1];
  const float4 adv = *(const float4*)(ad2 + (size_t)n * 4);

  float d0 = 0.f, d1 = 0.f, d2 = 0.f;
  float a0 = 0.f, a1 = 0.f, a2 = 0.f, a3 = 0.f, a4 = 0.f, a5 = 0.f;
  for (int j = start + r; j < end; j += 16) {
    int s = esw[j].x;
    float4 asv = *(const float4*)(as2 + (size_t)s * 4);
    float4 hlo = *(const float4*)(h2 + (size_t)s * 8);
    float2 hhi = *(const float2*)(h2 + (size_t)s * 8 + 4);
    float e0 = __expf(leaky(asv.x + adv.x));
    float e1 = __expf(leaky(asv.y + adv.y));
    float e2 = __expf(leaky(asv.z + adv.z));
    d0 += e0; d1 += e1; d2 += e2;
    a0 += e0 * hlo.x; a1 += e0 * hlo.y;
    a2 += e1 * hlo.z; a3 += e1 * hlo.w;
    a4 += e2 * hhi.x; a5 += e2 * hhi.y;
  }
#pragma unroll
  for (int m = 8; m >= 1; m >>= 1) {
    d0 += __shfl_xor(d0, m, 64); d1 += __shfl_xor(d1, m, 64); d2 += __shfl_xor(d2, m, 64);
    a0 += __shfl_xor(a0, m, 64); a1 += __shfl_xor(a1, m, 64); a2 += __shfl_xor(a2, m, 64);
    a3 += __shfl_xor(a3, m, 64); a4 += __shfl_xor(a4, m, 64); a5 += __shfl_xor(a5, m, 64);
  }
  if (r == 0) {
    float o0 = (a0 / d0 + a2 / d1 + a4 / d2) * (1.f / 3.f) + bias2[0];
    float o1 = (a1 / d0 + a3 / d1 + a5 / d2) * (1.f / 3.f) + bias2[1];
    *(float2*)(out + (size_t)n * 2) = make_float2(o0, o1);
  }
}

// ---------------------------------------------------------------------------
extern "C" void kernel_launch(void* const* d_in, const int* in_sizes, int n_in,
                              void* d_out, int out_size, void* d_ws, size_t ws_size,
                              hipStream_t stream) {
  const float* x        = (const float*)d_in[0];
  const int*   ei       = (const int*)d_in[1];
  const float* W1       = (const float*)d_in[2];
  const float* att_src1 = (const float*)d_in[3];
  const float* att_dst1 = (const float*)d_in[4];
  const float* bias1    = (const float*)d_in[5];
  const float* W2       = (const float*)d_in[6];
  const float* att_src2 = (const float*)d_in[7];
  const float* att_dst2 = (const float*)d_in[8];
  const float* bias2    = (const float*)d_in[9];
  float* out = (float*)d_out;

  char* w = (char*)d_ws;
  auto alloc = [&](size_t bytes) {
    char* p = w;
    w += (bytes + 255) & ~(size_t)255;
    return p;
  };
  unsigned short* h1u    = (unsigned short*)alloc((size_t)N_NODES * C_HID * 2);  // 12.8 MB
  unsigned short* Wswz   = (unsigned short*)alloc((size_t)C_IN * C_HID * 2 * 2); // 256 KB
  float*          v1s    = (float*)alloc((size_t)C_IN * 4);
  float*          v1d    = (float*)alloc((size_t)C_IN * 4);
  float*          a_src1 = (float*)alloc((size_t)N_NODES * 4);
  float*          a_dst1 = (float*)alloc((size_t)N_NODES * 4);
  int*            deg    = (int*)alloc((size_t)N_NODES * 4);
  int*            rowptr = (int*)alloc((size_t)(N_NODES + 4) * 4);
  int*            cursor = (int*)alloc((size_t)N_NODES * 4);
  int2*           esw    = (int2*)alloc((size_t)E_TOT * 8);                      // 6.8 MB
  float*          h2     = (float*)alloc((size_t)N_NODES * 8 * 4);
  float*          as2    = (float*)alloc((size_t)N_NODES * 4 * 4);
  float*          ad2    = (float*)alloc((size_t)N_NODES * 4 * 4);

  (void)hipMemsetAsync(deg, 0, (size_t)N_NODES * 4, stream);

  prep_v_kernel<<<C_IN / 4, 256, 0, stream>>>(W1, att_src1, att_dst1, v1s, v1d);
  prep_w_kernel<<<32, 256, 0, stream>>>(W1, Wswz);
  deg_kernel<<<(N_EDGES + 255) / 256, 256, 0, stream>>>(ei, deg);
  scan_kernel<<<1, 1024, 0, stream>>>(deg, rowptr, cursor);
  lin1_kernel<<<(N_NODES + 63) / 64, 256, 0, stream>>>(x, Wswz, v1s, v1d,
                                                       h1u, a_src1, a_dst1);
  bucket_kernel<<<(E_TOT + 255) / 256, 256, 0, stream>>>(ei, cursor, a_src1, a_dst1, esw);
  agg1_kernel<<<(N_NODES + 3) / 4, 256, 0, stream>>>(h1u, esw, rowptr, bias1, W2,
                                                     att_src2, att_dst2, h2, as2, ad2);
  agg2_kernel<<<(N_NODES + 15) / 16, 256, 0, stream>>>(h2, as2, ad2, rowptr, esw, bias2, out);
}